// Round 7
// baseline (632.304 us; speedup 1.0000x reference)
//
#include <hip/hip_runtime.h>

// TaxoRec forward pipeline on MI355X — round 7.
// Node feature rows padded to 128 f32 (512 B): cols 0..62 enc1, 63..125 enc2.
// CSR build: hist -> hierarchical scan -> radix-partition scatter.
// Gather: 16-edge unrolled inner loop (8 row-loads in flight per half-wave).
// Layer 3 gather fused with expmap; shifted store done via lane shuffles
// (no LDS, no barrier). hyper_agg: K-split tiled GEMM + combine.

#define KSPLIT 4
#define NBUK 96          // N / 512

__device__ __forceinline__ float wsum(float v) {
#pragma unroll
  for (int m = 32; m; m >>= 1) v += __shfl_xor(v, m, 64);
  return v;
}

__device__ __forceinline__ float logmap_scale(float ss) {
  float x0 = sqrtf(1.0f + ss);
  float alpha = fmaxf(x0, 1.0f + 1e-7f);
  float rnorm = sqrtf(fmaxf(ss, 1e-15f));
  return acoshf(alpha) / rnorm;
}

// xt[n,0:63) = logmap0(projx(emb[n])); rows < NU also get cols 63..125 from ugr.
__global__ __launch_bounds__(256) void k_node_prep(
    const float* __restrict__ emb, const float* __restrict__ ugr,
    float* __restrict__ xt, int N, int NU) {
  int n = blockIdx.x * 4 + (threadIdx.x >> 6);
  if (n >= N) return;
  int lane = threadIdx.x & 63;
  size_t base = (size_t)n * 128;
  float r1 = (lane < 63) ? emb[(size_t)n * 64 + 1 + lane] : 0.0f;
  float sc1 = logmap_scale(wsum(r1 * r1));
  if (lane < 63) xt[base + lane] = sc1 * r1;
  if (lane == 63) { xt[base + 126] = 0.0f; xt[base + 127] = 0.0f; }
  if (n < NU) {
    float r2 = (lane < 63) ? ugr[(size_t)n * 64 + 1 + lane] : 0.0f;
    float sc2 = logmap_scale(wsum(r2 * r2));
    if (lane < 63) xt[base + 63 + lane] = sc2 * r2;
  }
}

// per tag: gkg[t, 0:63) = gamma * k, gkg[t, 63] = gamma
__global__ __launch_bounds__(256) void k_tag_prep(
    const float* __restrict__ Tw, float* __restrict__ gkg, int TAGS) {
  int t = blockIdx.x * 4 + (threadIdx.x >> 6);
  if (t >= TAGS) return;
  int lane = threadIdx.x & 63;
  float r = (lane < 63) ? Tw[(size_t)t * 64 + 1 + lane] : 0.0f;
  float ss = wsum(r * r);
  float x0 = sqrtf(1.0f + ss);
  float p = r / (x0 + 1.0f);          // l2p (sk = 1)
  float sp = wsum(p * p);
  float k = 2.0f * p / (1.0f + sp);   // p2k
  float sk2 = wsum(k * k);
  float gamma = 1.0f / sqrtf(fmaxf(1.0f - sk2, 1e-15f));
  gkg[(size_t)t * 64 + lane] = (lane < 63) ? gamma * k : gamma;
}

// hyper_agg GEMM, K-split: block (bx, ksp) computes partial[ksp][64][64].
__global__ __launch_bounds__(256) void k_hyper(
    const float* __restrict__ sps, const float* __restrict__ gkg,
    float* __restrict__ pb, int NI) {
  __shared__ float s_tile[64][36];
  __shared__ float g_tile[32][64];
  int tid = threadIdx.x;
  int tx = tid & 15, ty = tid >> 4;
  int sx = tid & 7,  sy = tid >> 3;
  int gx = tid & 15, gy = tid >> 4;
  int ib = blockIdx.x * 64;
  int kbase = blockIdx.y * 256;
  float acc[4][4];
#pragma unroll
  for (int c = 0; c < 4; ++c)
#pragma unroll
    for (int d = 0; d < 4; ++d) acc[c][d] = 0.0f;

  const float4* sps4 = (const float4*)sps;
  const float4* gkg4 = (const float4*)gkg;

  for (int kc = 0; kc < 8; ++kc) {
    int t4b = (kbase >> 2) + kc * 8;
#pragma unroll
    for (int r = 0; r < 2; ++r) {
      int row = sy + 32 * r;
      *(float4*)&s_tile[row][sx * 4] = sps4[(size_t)(ib + row) * 256 + t4b + sx];
      int grow = gy + 16 * r;
      *(float4*)&g_tile[grow][gx * 4] =
          gkg4[(size_t)(kbase + kc * 32 + grow) * 16 + gx];
    }
    __syncthreads();
#pragma unroll
    for (int tg = 0; tg < 8; ++tg) {
      float4 s4[4], g4[4];
#pragma unroll
      for (int c = 0; c < 4; ++c) s4[c] = *(const float4*)&s_tile[ty * 4 + c][tg * 4];
#pragma unroll
      for (int j = 0; j < 4; ++j) g4[j] = *(const float4*)&g_tile[tg * 4 + j][tx * 4];
#pragma unroll
      for (int c = 0; c < 4; ++c) {
        float sv[4] = {s4[c].x, s4[c].y, s4[c].z, s4[c].w};
#pragma unroll
        for (int j = 0; j < 4; ++j) {
          acc[c][0] = fmaf(sv[j], g4[j].x, acc[c][0]);
          acc[c][1] = fmaf(sv[j], g4[j].y, acc[c][1]);
          acc[c][2] = fmaf(sv[j], g4[j].z, acc[c][2]);
          acc[c][3] = fmaf(sv[j], g4[j].w, acc[c][3]);
        }
      }
    }
    __syncthreads();
  }

  float* dst = pb + ((size_t)blockIdx.y * NI + ib) * 64;
#pragma unroll
  for (int c = 0; c < 4; ++c)
    *(float4*)&dst[(size_t)(ty * 4 + c) * 64 + tx * 4] =
        make_float4(acc[c][0], acc[c][1], acc[c][2], acc[c][3]);
}

// sum the KSPLIT partials, then k2p -> p2l -> logmap0; wave per item.
__global__ __launch_bounds__(256) void k_combine(
    const float* __restrict__ pb, float* __restrict__ xt, int NI, int NU) {
  int i = blockIdx.x * 4 + (threadIdx.x >> 6);
  if (i >= NI) return;
  int lane = threadIdx.x & 63;
  float v = 0.0f;
#pragma unroll
  for (int s = 0; s < KSPLIT; ++s) v += pb[((size_t)s * NI + i) * 64 + lane];
  float den = fmaxf(__shfl(v, 63, 64), 1e-15f);
  float y = v / den;
  float sy = wsum((lane < 63) ? y * y : 0.0f);
  float dk = 1.0f + sqrtf(fmaxf(1.0f - sy, 1e-15f));
  float q = y / dk;
  float nq = wsum((lane < 63) ? q * q : 0.0f);
  float f = 1.0f / (1.0f - nq + 1e-6f);
  float row0 = (1.0f + nq) * f;
  float r = 2.0f * q * f;
  float srr = wsum((lane < 63) ? r * r : 0.0f);
  float alpha = fmaxf(row0, 1.0f + 1e-7f);
  float scale = acoshf(alpha) / sqrtf(fmaxf(srr, 1e-15f));
  if (lane < 63)
    xt[(size_t)(NU + i) * 128 + 63 + lane] = scale * r;
}

// ---- CSR build ----------------------------------------------------------

__global__ __launch_bounds__(256) void k_hist(
    const int* __restrict__ edst, int* __restrict__ pos, int E) {
  int e = blockIdx.x * blockDim.x + threadIdx.x;
  if (e < E) atomicAdd(&pos[edst[e]], 1);
}

__global__ __launch_bounds__(256) void kb1(const int* __restrict__ pos,
                                           int* __restrict__ bsum) {
  __shared__ int red[4];
  int v = pos[blockIdx.x * 256 + threadIdx.x];
#pragma unroll
  for (int m = 32; m; m >>= 1) v += __shfl_xor(v, m, 64);
  if ((threadIdx.x & 63) == 0) red[threadIdx.x >> 6] = v;
  __syncthreads();
  if (threadIdx.x == 0) bsum[blockIdx.x] = red[0] + red[1] + red[2] + red[3];
}

__global__ __launch_bounds__(256) void kb2(const int* __restrict__ bsum,
                                           int* __restrict__ bof,
                                           int* __restrict__ off,
                                           int NB, int N, int E) {
  __shared__ int sc[256];
  int t = threadIdx.x;
  int mine = (t < NB) ? bsum[t] : 0;
  sc[t] = mine;
  __syncthreads();
  for (int d = 1; d < 256; d <<= 1) {
    int v = (t >= d) ? sc[t - d] : 0;
    __syncthreads();
    sc[t] += v;
    __syncthreads();
  }
  if (t < NB) bof[t] = sc[t] - mine;   // exclusive
  if (t == 0) off[N] = E;
}

__global__ __launch_bounds__(256) void kb3(int* pos, int* __restrict__ off,
                                           const int* __restrict__ bof) {
  __shared__ int sc[256];
  int t = threadIdx.x;
  int i = blockIdx.x * 256 + t;
  int d = pos[i];
  sc[t] = d;
  __syncthreads();
  for (int s = 1; s < 256; s <<= 1) {
    int v = (t >= s) ? sc[t - s] : 0;
    __syncthreads();
    sc[t] += v;
    __syncthreads();
  }
  int val = bof[blockIdx.x] + sc[t] - d;
  off[i] = val;
  pos[i] = val;
}

// Pass A: radix partition edges by bucket = dst>>9 into staged runs.
__global__ __launch_bounds__(256) void k_passA(
    const int* __restrict__ esrc, const int* __restrict__ edst,
    const float* __restrict__ ew, const int* __restrict__ off,
    int* __restrict__ bcur, int2* __restrict__ stage) {
  __shared__ int lh[128];
  __shared__ int lscan[128];
  __shared__ int lcur[128];
  __shared__ int gb[128];
  __shared__ unsigned int keyb[2048];
  __shared__ float wvb[2048];
  int tid = threadIdx.x;
  int base = blockIdx.x * 2048;
  if (tid < 128) lh[tid] = 0;
  __syncthreads();
  unsigned int key[8]; float wv[8];
#pragma unroll
  for (int r = 0; r < 8; ++r) {
    int e = base + r * 256 + tid;
    int d = edst[e];
    key[r] = ((unsigned int)d << 16) | (unsigned int)esrc[e];
    wv[r] = ew[e];
    atomicAdd(&lh[d >> 9], 1);
  }
  __syncthreads();
  if (tid < 128) lscan[tid] = lh[tid];
  __syncthreads();
  for (int d = 1; d < 128; d <<= 1) {
    int v = (tid < 128 && tid >= d) ? lscan[tid - d] : 0;
    __syncthreads();
    if (tid < 128) lscan[tid] += v;
    __syncthreads();
  }
  if (tid < 128) {
    int excl = lscan[tid] - lh[tid];
    lscan[tid] = excl;
    lcur[tid] = 0;
    if (tid < NBUK && lh[tid] > 0)
      gb[tid] = off[tid << 9] + atomicAdd(&bcur[tid], lh[tid]);
  }
  __syncthreads();
#pragma unroll
  for (int r = 0; r < 8; ++r) {
    int b = key[r] >> 25;
    int lp = lscan[b] + atomicAdd(&lcur[b], 1);
    keyb[lp] = key[r];
    wvb[lp] = wv[r];
  }
  __syncthreads();
#pragma unroll
  for (int r = 0; r < 8; ++r) {
    int i = r * 256 + tid;
    unsigned int k2 = keyb[i];
    int b = k2 >> 25;
    stage[gb[b] + (i - lscan[b])] = make_int2((int)k2, __float_as_int(wvb[i]));
  }
}

// Pass B: per-bucket scatter of staged records to final CSR slots.
__global__ __launch_bounds__(256) void k_passB(
    const int2* __restrict__ stage, const int* __restrict__ off,
    int* __restrict__ pos, int2* __restrict__ rec) {
  int b = blockIdx.x >> 3, part = blockIdx.x & 7;
  int bb = off[b << 9], be = off[(b + 1) << 9];
  int len = be - bb;
  int pbeg = bb + (len * part >> 3);
  int pend = bb + (len * (part + 1) >> 3);
  for (int i = pbeg + threadIdx.x; i < pend; i += 256) {
    int2 r = stage[i];
    unsigned int k2 = (unsigned int)r.x;
    int d = (int)(k2 >> 16);
    int p = atomicAdd(&pos[d], 1);
    rec[p] = make_int2((int)(k2 & 0xFFFF), r.y);
  }
}

// ---- gather core: segment-sum row for dst n; 16 edges/iter, 8 row-loads
// in flight per half-wave. Returns merged row chunk (lane&31) in all lanes.
__device__ __forceinline__ float4 gather_row(
    const float* __restrict__ cur, const int* __restrict__ off,
    const int2* __restrict__ rec, int n, int lane) {
  int half = lane >> 5;
  int q = lane & 31;
  const float4* cq = (const float4*)cur + q;
  int beg = off[n], end = off[n + 1];
  float4 acc = make_float4(0.0f, 0.0f, 0.0f, 0.0f);
  for (int j = beg; j < end; j += 64) {
    int cnt = min(64, end - j);
    int sv = 0; float wv = 0.0f;
    if (lane < cnt) {
      int2 rc = rec[j + lane];
      sv = rc.x;
      wv = __int_as_float(rc.y);
    }
    int k = 0;
    for (; k + 16 <= cnt; k += 16) {
      int s[8]; float w[8]; float4 v[8];
#pragma unroll
      for (int u = 0; u < 8; ++u) {
        int e = k + 2 * u + half;
        s[u] = __shfl(sv, e, 64);
        w[u] = __shfl(wv, e, 64);
      }
#pragma unroll
      for (int u = 0; u < 8; ++u) v[u] = cq[(size_t)s[u] * 32];
#pragma unroll
      for (int u = 0; u < 8; ++u) {
        acc.x = fmaf(w[u], v[u].x, acc.x);
        acc.y = fmaf(w[u], v[u].y, acc.y);
        acc.z = fmaf(w[u], v[u].z, acc.z);
        acc.w = fmaf(w[u], v[u].w, acc.w);
      }
    }
    for (; k + 8 <= cnt; k += 8) {
      int s[4]; float w[4]; float4 v[4];
#pragma unroll
      for (int u = 0; u < 4; ++u) {
        int e = k + 2 * u + half;
        s[u] = __shfl(sv, e, 64);
        w[u] = __shfl(wv, e, 64);
      }
#pragma unroll
      for (int u = 0; u < 4; ++u) v[u] = cq[(size_t)s[u] * 32];
#pragma unroll
      for (int u = 0; u < 4; ++u) {
        acc.x = fmaf(w[u], v[u].x, acc.x);
        acc.y = fmaf(w[u], v[u].y, acc.y);
        acc.z = fmaf(w[u], v[u].z, acc.z);
        acc.w = fmaf(w[u], v[u].w, acc.w);
      }
    }
    for (; k + 2 <= cnt; k += 2) {
      int e = k + half;
      int s0 = __shfl(sv, e, 64);
      float w0 = __shfl(wv, e, 64);
      float4 v = cq[(size_t)s0 * 32];
      acc.x = fmaf(w0, v.x, acc.x);
      acc.y = fmaf(w0, v.y, acc.y);
      acc.z = fmaf(w0, v.z, acc.z);
      acc.w = fmaf(w0, v.w, acc.w);
    }
    if (k < cnt) {
      int s0 = __shfl(sv, k, 64);
      float w0 = __shfl(wv, k, 64);
      if (half == 0) {
        float4 v = cq[(size_t)s0 * 32];
        acc.x = fmaf(w0, v.x, acc.x);
        acc.y = fmaf(w0, v.y, acc.y);
        acc.z = fmaf(w0, v.z, acc.z);
        acc.w = fmaf(w0, v.w, acc.w);
      }
    }
  }
  acc.x += __shfl_xor(acc.x, 32, 64);
  acc.y += __shfl_xor(acc.y, 32, 64);
  acc.z += __shfl_xor(acc.z, 32, 64);
  acc.w += __shfl_xor(acc.w, 32, 64);
  return acc;
}

// layers 1,2: plain gather, write full row once.
__global__ __launch_bounds__(256) void k_gather(
    const float* __restrict__ cur, float* __restrict__ nxt,
    const int* __restrict__ off, const int2* __restrict__ rec, int N) {
  int n = blockIdx.x * 4 + (threadIdx.x >> 6);
  if (n >= N) return;
  int lane = threadIdx.x & 63;
  float4 acc = gather_row(cur, off, rec, n, lane);
  if (lane < 32) ((float4*)(nxt + (size_t)n * 128))[lane] = acc;
}

// layer 3 fused with expmap: h[n] = [expmap0(enc1) | expmap0(enc2)].
// Shifted store via lane shuffles: out col c: c==0 -> cosh0; 1..63 ->
// s0*a[c-1]; c==64 -> cosh1; 65..127 -> s1*a[c-2]. Lane q holds a[4q..4q+3];
// prev lane supplies a[4q-2], a[4q-1]. h aliases b1 (row read before write).
__global__ __launch_bounds__(256) void k_gather_exp(
    const float* __restrict__ cur, const float* b1, const float* __restrict__ b2,
    const int* __restrict__ off, const int2* __restrict__ rec,
    float* h, int N) {
  int n = blockIdx.x * 4 + (threadIdx.x >> 6);
  if (n >= N) return;
  int lane = threadIdx.x & 63;
  int q = lane & 31;
  float4 a3 = gather_row(cur, off, rec, n, lane);
  size_t b = (size_t)n * 128;
  float4 r1 = ((const float4*)(b1 + b))[q];
  float4 r2 = ((const float4*)(b2 + b))[q];
  float vv[4] = {a3.x + r1.x + r2.x, a3.y + r1.y + r2.y,
                 a3.z + r1.z + r2.z, a3.w + r1.w + r2.w};
  // split sums of squares at col 63 (cols 126/127 are zero)
  float p0 = 0.0f, p1 = 0.0f;
#pragma unroll
  for (int i = 0; i < 4; ++i) {
    int c = 4 * q + i;
    if (c < 63) p0 += vv[i] * vv[i]; else p1 += vv[i] * vv[i];
  }
  float ss0 = 0.5f * wsum(p0);         // halves hold duplicate copies
  float ss1 = 0.5f * wsum(p1);
  float nn0 = sqrtf(fmaxf(ss0, 1e-15f)), nn1 = sqrtf(fmaxf(ss1, 1e-15f));
  float s0 = sinhf(nn0) / nn0, s1 = sinhf(nn1) / nn1;
  int prev = (lane == 0) ? 0 : lane - 1;
  float pv2 = __shfl(vv[2], prev, 64);
  float pv3 = __shfl(vv[3], prev, 64);
  if (lane < 32) {
    float4 o;
    if (q < 16) {
      o.x = (q == 0) ? coshf(nn0) : s0 * pv3;
      o.y = s0 * vv[0]; o.z = s0 * vv[1]; o.w = s0 * vv[2];
    } else {
      o.x = (q == 16) ? coshf(nn1) : s1 * pv2;
      o.y = s1 * pv3; o.z = s1 * vv[0]; o.w = s1 * vv[1];
    }
    ((float4*)(h + b))[q] = o;
  }
}

// out[b] = min(dist2(.,.),50) + min(dist2(.,.),15); 4 pairs per wave.
__global__ __launch_bounds__(256) void k_score(
    const float* __restrict__ h, const int* __restrict__ idx,
    float* __restrict__ out, int B) {
  int w = blockIdx.x * 4 + (threadIdx.x >> 6);
  int lane = threadIdx.x & 63;
  int b0 = w * 4;
  if (b0 >= B) return;
  int np = min(4, B - b0);
  float2 hu[4], hv[4];
#pragma unroll
  for (int p = 0; p < 4; ++p) {
    int bb = b0 + ((p < np) ? p : 0);
    int u = idx[2 * bb], v = idx[2 * bb + 1];
    hu[p] = ((const float2*)(h + (size_t)u * 128))[lane];
    hv[p] = ((const float2*)(h + (size_t)v * 128))[lane];
  }
#pragma unroll
  for (int p = 0; p < 4; ++p) {
    if (p >= np) break;
    float px = hu[p].x * hv[p].x;
    if (lane == 0 || lane == 32) px = -px;   // time comps at cols 0 and 64
    float pp = px + hu[p].y * hv[p].y;
#pragma unroll
    for (int m = 1; m < 32; m <<= 1) pp += __shfl_xor(pp, m, 64);
    float dd = fmaxf(-pp, 1.0f + 1e-7f);
    float a = acoshf(dd);
    float s = fminf(a * a, (lane < 32) ? 50.0f : 15.0f);
    s += __shfl_xor(s, 32, 64);
    if (lane == 0) out[b0 + p] = s;
  }
}

extern "C" void kernel_launch(void* const* d_in, const int* in_sizes, int n_in,
                              void* d_out, int out_size, void* d_ws, size_t ws_size,
                              hipStream_t stream) {
  const float* emb = (const float*)d_in[0];
  const float* Tw  = (const float*)d_in[1];
  const float* ugr = (const float*)d_in[2];
  const float* sps = (const float*)d_in[3];
  const float* ew  = (const float*)d_in[4];
  const int* esrc  = (const int*)d_in[5];
  const int* edst  = (const int*)d_in[6];
  const int* idx   = (const int*)d_in[7];
  float* out = (float*)d_out;

  const int N    = in_sizes[0] / 64;   // 49152
  const int TAGS = in_sizes[1] / 64;   // 1024
  const int NU   = in_sizes[2] / 64;   // 8192
  const int NI   = in_sizes[3] / TAGS; // 40960
  const int E    = in_sizes[4];        // 1572864
  const int B    = in_sizes[7] / 2;    // 131072
  const int NB   = N / 256;            // 192 scan blocks

  size_t rowsz = (size_t)N * 128 * sizeof(float);
  char* ws = (char*)d_ws;
  float* xt  = (float*)(ws);               // encoder layer-0 input
  float* b1  = (float*)(ws + rowsz);       // layer1 out; pb alias; h alias
  float* b2  = (float*)(ws + 2 * rowsz);   // layer2 out; stage alias
  float* gkg = (float*)(ws + 3 * rowsz);   // TAGS x 64
  size_t o = 3 * rowsz + (size_t)TAGS * 64 * sizeof(float);
  int* off  = (int*)(ws + o);  o += (size_t)(N + 1) * sizeof(int);
  int* pos  = (int*)(ws + o);  o += (size_t)N * sizeof(int);
  int* bsum = (int*)(ws + o);  o += (size_t)NB * sizeof(int);
  int* bof  = (int*)(ws + o);  o += (size_t)NB * sizeof(int);
  int* bcur = (int*)(ws + o);  o += (size_t)NBUK * sizeof(int);
  o = (o + 7) & ~(size_t)7;
  int2* rec = (int2*)(ws + o);             // E records (src, w)
  int2* stage = (int2*)b2;                 // E staged records (dead before gather2)
  float* pb = b1;                          // KSPLIT x NI x 64 partials
  float* h  = b1;                          // final embeddings, in-place over b1

  // CSR build
  hipMemsetAsync(pos, 0, (size_t)N * sizeof(int), stream);
  hipMemsetAsync(bcur, 0, (size_t)NBUK * sizeof(int), stream);
  k_hist<<<(E + 255) / 256, 256, 0, stream>>>(edst, pos, E);
  kb1<<<NB, 256, 0, stream>>>(pos, bsum);
  kb2<<<1, 256, 0, stream>>>(bsum, bof, off, NB, N, E);
  kb3<<<NB, 256, 0, stream>>>(pos, off, bof);
  k_passA<<<E / 2048, 256, 0, stream>>>(esrc, edst, ew, off, bcur, stage);
  k_passB<<<NBUK * 8, 256, 0, stream>>>(stage, off, pos, rec);

  // feature prep
  k_node_prep<<<(N + 3) / 4, 256, 0, stream>>>(emb, ugr, xt, N, NU);
  k_tag_prep<<<(TAGS + 3) / 4, 256, 0, stream>>>(Tw, gkg, TAGS);
  dim3 hgrid(NI / 64, KSPLIT);
  k_hyper<<<hgrid, 256, 0, stream>>>(sps, gkg, pb, NI);
  k_combine<<<(NI + 3) / 4, 256, 0, stream>>>(pb, xt, NI, NU);

  // 3 encoder layers (gather-side, no atomics); layer 3 fused with expmap
  k_gather<<<(N + 3) / 4, 256, 0, stream>>>(xt, b1, off, rec, N);
  k_gather<<<(N + 3) / 4, 256, 0, stream>>>(b1, b2, off, rec, N);
  k_gather_exp<<<(N + 3) / 4, 256, 0, stream>>>(b2, b1, b2, off, rec, h, N);

  k_score<<<(B / 4 + 3) / 4, 256, 0, stream>>>(h, idx, out, B);
}

// Round 8
// 546.648 us; speedup vs baseline: 1.1567x; 1.1567x over previous
//
#include <hip/hip_runtime.h>

// TaxoRec forward pipeline on MI355X — round 8.
// Node feature rows padded to 128 f32 (512 B): cols 0..62 enc1, 63..125 enc2.
// CSR build (restructured): passA self-allocating radix partition into
// fixed-capacity buckets (CAP) -> 96-entry bucket scan -> passB2 computes
// per-dst offsets IN-KERNEL (LDS hist+scan per bucket) and scatters with LDS
// cursors. k_hist / hierarchical scan / global per-dst atomics all deleted.
// Gather: 16-edge unrolled loop (structural floor ~3.6 TB/s L2-miss traffic).
// hyper_agg: K-split tiled GEMM + combine.

#define KSPLIT 4
#define NBUK 96          // N / 512
#define CAP 18432        // bucket capacity; mean 16384, sigma 127 -> safe

__device__ __forceinline__ float wsum(float v) {
#pragma unroll
  for (int m = 32; m; m >>= 1) v += __shfl_xor(v, m, 64);
  return v;
}

__device__ __forceinline__ float logmap_scale(float ss) {
  float x0 = sqrtf(1.0f + ss);
  float alpha = fmaxf(x0, 1.0f + 1e-7f);
  float rnorm = sqrtf(fmaxf(ss, 1e-15f));
  return acoshf(alpha) / rnorm;
}

// rows [0,N): xt[n,0:63) = logmap0(projx(emb[n])), users also cols 63..125.
// rows [N,N+TAGS): gkg[t] = [gamma*k | gamma].
__global__ __launch_bounds__(256) void k_prep(
    const float* __restrict__ emb, const float* __restrict__ ugr,
    const float* __restrict__ Tw, float* __restrict__ xt,
    float* __restrict__ gkg, int N, int NU, int TAGS) {
  int n = blockIdx.x * 4 + (threadIdx.x >> 6);
  int lane = threadIdx.x & 63;
  if (n < N) {
    size_t base = (size_t)n * 128;
    float r1 = (lane < 63) ? emb[(size_t)n * 64 + 1 + lane] : 0.0f;
    float sc1 = logmap_scale(wsum(r1 * r1));
    if (lane < 63) xt[base + lane] = sc1 * r1;
    if (lane == 63) { xt[base + 126] = 0.0f; xt[base + 127] = 0.0f; }
    if (n < NU) {
      float r2 = (lane < 63) ? ugr[(size_t)n * 64 + 1 + lane] : 0.0f;
      float sc2 = logmap_scale(wsum(r2 * r2));
      if (lane < 63) xt[base + 63 + lane] = sc2 * r2;
    }
  } else if (n < N + TAGS) {
    int t = n - N;
    float r = (lane < 63) ? Tw[(size_t)t * 64 + 1 + lane] : 0.0f;
    float ss = wsum(r * r);
    float x0 = sqrtf(1.0f + ss);
    float p = r / (x0 + 1.0f);          // l2p (sk = 1)
    float sp = wsum(p * p);
    float k = 2.0f * p / (1.0f + sp);   // p2k
    float sk2 = wsum(k * k);
    float gamma = 1.0f / sqrtf(fmaxf(1.0f - sk2, 1e-15f));
    gkg[(size_t)t * 64 + lane] = (lane < 63) ? gamma * k : gamma;
  }
}

// hyper_agg GEMM, K-split: block (bx, ksp) computes partial[ksp][64][64].
__global__ __launch_bounds__(256) void k_hyper(
    const float* __restrict__ sps, const float* __restrict__ gkg,
    float* __restrict__ pb, int NI) {
  __shared__ float s_tile[64][36];
  __shared__ float g_tile[32][64];
  int tid = threadIdx.x;
  int tx = tid & 15, ty = tid >> 4;
  int sx = tid & 7,  sy = tid >> 3;
  int gx = tid & 15, gy = tid >> 4;
  int ib = blockIdx.x * 64;
  int kbase = blockIdx.y * 256;
  float acc[4][4];
#pragma unroll
  for (int c = 0; c < 4; ++c)
#pragma unroll
    for (int d = 0; d < 4; ++d) acc[c][d] = 0.0f;

  const float4* sps4 = (const float4*)sps;
  const float4* gkg4 = (const float4*)gkg;

  for (int kc = 0; kc < 8; ++kc) {
    int t4b = (kbase >> 2) + kc * 8;
#pragma unroll
    for (int r = 0; r < 2; ++r) {
      int row = sy + 32 * r;
      *(float4*)&s_tile[row][sx * 4] = sps4[(size_t)(ib + row) * 256 + t4b + sx];
      int grow = gy + 16 * r;
      *(float4*)&g_tile[grow][gx * 4] =
          gkg4[(size_t)(kbase + kc * 32 + grow) * 16 + gx];
    }
    __syncthreads();
#pragma unroll
    for (int tg = 0; tg < 8; ++tg) {
      float4 s4[4], g4[4];
#pragma unroll
      for (int c = 0; c < 4; ++c) s4[c] = *(const float4*)&s_tile[ty * 4 + c][tg * 4];
#pragma unroll
      for (int j = 0; j < 4; ++j) g4[j] = *(const float4*)&g_tile[tg * 4 + j][tx * 4];
#pragma unroll
      for (int c = 0; c < 4; ++c) {
        float sv[4] = {s4[c].x, s4[c].y, s4[c].z, s4[c].w};
#pragma unroll
        for (int j = 0; j < 4; ++j) {
          acc[c][0] = fmaf(sv[j], g4[j].x, acc[c][0]);
          acc[c][1] = fmaf(sv[j], g4[j].y, acc[c][1]);
          acc[c][2] = fmaf(sv[j], g4[j].z, acc[c][2]);
          acc[c][3] = fmaf(sv[j], g4[j].w, acc[c][3]);
        }
      }
    }
    __syncthreads();
  }

  float* dst = pb + ((size_t)blockIdx.y * NI + ib) * 64;
#pragma unroll
  for (int c = 0; c < 4; ++c)
    *(float4*)&dst[(size_t)(ty * 4 + c) * 64 + tx * 4] =
        make_float4(acc[c][0], acc[c][1], acc[c][2], acc[c][3]);
}

// sum the KSPLIT partials, then k2p -> p2l -> logmap0; wave per item.
__global__ __launch_bounds__(256) void k_combine(
    const float* __restrict__ pb, float* __restrict__ xt, int NI, int NU) {
  int i = blockIdx.x * 4 + (threadIdx.x >> 6);
  if (i >= NI) return;
  int lane = threadIdx.x & 63;
  float v = 0.0f;
#pragma unroll
  for (int s = 0; s < KSPLIT; ++s) v += pb[((size_t)s * NI + i) * 64 + lane];
  float den = fmaxf(__shfl(v, 63, 64), 1e-15f);
  float y = v / den;
  float sy = wsum((lane < 63) ? y * y : 0.0f);
  float dk = 1.0f + sqrtf(fmaxf(1.0f - sy, 1e-15f));
  float q = y / dk;
  float nq = wsum((lane < 63) ? q * q : 0.0f);
  float f = 1.0f / (1.0f - nq + 1e-6f);
  float row0 = (1.0f + nq) * f;
  float r = 2.0f * q * f;
  float srr = wsum((lane < 63) ? r * r : 0.0f);
  float alpha = fmaxf(row0, 1.0f + 1e-7f);
  float scale = acoshf(alpha) / sqrtf(fmaxf(srr, 1e-15f));
  if (lane < 63)
    xt[(size_t)(NU + i) * 128 + 63 + lane] = scale * r;
}

// ---- CSR build ----------------------------------------------------------

// Pass A: radix partition edges by bucket = dst>>9 into fixed-capacity
// staged runs (self-allocating via bcur; no precomputed offsets needed).
__global__ __launch_bounds__(256) void k_passA(
    const int* __restrict__ esrc, const int* __restrict__ edst,
    const float* __restrict__ ew, int* __restrict__ bcur,
    int2* __restrict__ stage) {
  __shared__ int lh[128];
  __shared__ int lscan[128];
  __shared__ int lcur[128];
  __shared__ int gb[128];
  __shared__ unsigned int keyb[2048];
  __shared__ float wvb[2048];
  int tid = threadIdx.x;
  int base = blockIdx.x * 2048;
  if (tid < 128) lh[tid] = 0;
  __syncthreads();
  unsigned int key[8]; float wv[8];
#pragma unroll
  for (int r = 0; r < 8; ++r) {
    int e = base + r * 256 + tid;
    int d = edst[e];
    key[r] = ((unsigned int)d << 16) | (unsigned int)esrc[e];
    wv[r] = ew[e];
    atomicAdd(&lh[d >> 9], 1);
  }
  __syncthreads();
  if (tid < 128) lscan[tid] = lh[tid];
  __syncthreads();
  for (int d = 1; d < 128; d <<= 1) {
    int v = (tid < 128 && tid >= d) ? lscan[tid - d] : 0;
    __syncthreads();
    if (tid < 128) lscan[tid] += v;
    __syncthreads();
  }
  if (tid < 128) {
    int excl = lscan[tid] - lh[tid];
    lscan[tid] = excl;
    lcur[tid] = 0;
    if (tid < NBUK && lh[tid] > 0) {
      int rsv = atomicAdd(&bcur[tid], lh[tid]);
      gb[tid] = tid * CAP + rsv;
    }
  }
  __syncthreads();
#pragma unroll
  for (int r = 0; r < 8; ++r) {
    int b = key[r] >> 25;
    int lp = lscan[b] + atomicAdd(&lcur[b], 1);
    keyb[lp] = key[r];
    wvb[lp] = wv[r];
  }
  __syncthreads();
#pragma unroll
  for (int r = 0; r < 8; ++r) {
    int i = r * 256 + tid;
    unsigned int k2 = keyb[i];
    int b = k2 >> 25;
    stage[gb[b] + (i - lscan[b])] = make_int2((int)k2, __float_as_int(wvb[i]));
  }
}

// exclusive scan of the 96 bucket counts -> bbase; off[N] = E.
__global__ __launch_bounds__(128) void k_bscan(
    const int* __restrict__ bcur, int* __restrict__ bbase,
    int* __restrict__ off, int N, int E) {
  __shared__ int sc[128];
  int t = threadIdx.x;
  int v = (t < NBUK) ? min(bcur[t], CAP) : 0;
  sc[t] = v;
  __syncthreads();
  for (int d = 1; d < 128; d <<= 1) {
    int x = (t >= d) ? sc[t - d] : 0;
    __syncthreads();
    sc[t] += x;
    __syncthreads();
  }
  if (t < NBUK) bbase[t] = sc[t] - v;
  if (t == 0) off[N] = E;
}

// Pass B2: one block per bucket. LDS histogram over the bucket's 512 dsts,
// LDS scan -> per-dst offsets (written to off[]), then scatter staged
// records to final CSR slots via LDS cursors. No global atomics.
__global__ __launch_bounds__(256) void k_passB2(
    const int2* __restrict__ stage, const int* __restrict__ bcur,
    const int* __restrict__ bbase, int* __restrict__ off,
    int2* __restrict__ rec) {
  __shared__ int hist[512];
  __shared__ int pairs[256];
  __shared__ int cur[512];
  int b = blockIdx.x, tid = threadIdx.x;
  int cnt = min(bcur[b], CAP);
  const int2* sg = stage + (size_t)b * CAP;
  hist[tid] = 0; hist[tid + 256] = 0;
  __syncthreads();
  for (int i = tid; i < cnt; i += 256)
    atomicAdd(&hist[((unsigned int)sg[i].x >> 16) & 511], 1);
  __syncthreads();
  int h0 = hist[2 * tid], h1 = hist[2 * tid + 1];
  int ps = h0 + h1;
  pairs[tid] = ps;
  __syncthreads();
  for (int d = 1; d < 256; d <<= 1) {
    int v = (tid >= d) ? pairs[tid - d] : 0;
    __syncthreads();
    pairs[tid] += v;
    __syncthreads();
  }
  int base = bbase[b];
  int e0 = base + pairs[tid] - ps;     // exclusive prefix for dst 2*tid
  int e1 = e0 + h0;
  int gd = b * 512 + 2 * tid;
  off[gd] = e0;      cur[2 * tid] = e0;
  off[gd + 1] = e1;  cur[2 * tid + 1] = e1;
  __syncthreads();
  for (int i = tid; i < cnt; i += 256) {
    int2 r = sg[i];
    unsigned int k2 = (unsigned int)r.x;
    int d = (int)((k2 >> 16) & 511);
    int p = atomicAdd(&cur[d], 1);
    rec[p] = make_int2((int)(k2 & 0xFFFF), r.y);
  }
}

// ---- gather core: segment-sum row for dst n; 16 edges/iter, 8 row-loads
// in flight per half-wave. Returns merged row chunk (lane&31) in all lanes.
__device__ __forceinline__ float4 gather_row(
    const float* __restrict__ cur, const int* __restrict__ off,
    const int2* __restrict__ rec, int n, int lane) {
  int half = lane >> 5;
  int q = lane & 31;
  const float4* cq = (const float4*)cur + q;
  int beg = off[n], end = off[n + 1];
  float4 acc = make_float4(0.0f, 0.0f, 0.0f, 0.0f);
  for (int j = beg; j < end; j += 64) {
    int cnt = min(64, end - j);
    int sv = 0; float wv = 0.0f;
    if (lane < cnt) {
      int2 rc = rec[j + lane];
      sv = rc.x;
      wv = __int_as_float(rc.y);
    }
    int k = 0;
    for (; k + 16 <= cnt; k += 16) {
      int s[8]; float w[8]; float4 v[8];
#pragma unroll
      for (int u = 0; u < 8; ++u) {
        int e = k + 2 * u + half;
        s[u] = __shfl(sv, e, 64);
        w[u] = __shfl(wv, e, 64);
      }
#pragma unroll
      for (int u = 0; u < 8; ++u) v[u] = cq[(size_t)s[u] * 32];
#pragma unroll
      for (int u = 0; u < 8; ++u) {
        acc.x = fmaf(w[u], v[u].x, acc.x);
        acc.y = fmaf(w[u], v[u].y, acc.y);
        acc.z = fmaf(w[u], v[u].z, acc.z);
        acc.w = fmaf(w[u], v[u].w, acc.w);
      }
    }
    for (; k + 8 <= cnt; k += 8) {
      int s[4]; float w[4]; float4 v[4];
#pragma unroll
      for (int u = 0; u < 4; ++u) {
        int e = k + 2 * u + half;
        s[u] = __shfl(sv, e, 64);
        w[u] = __shfl(wv, e, 64);
      }
#pragma unroll
      for (int u = 0; u < 4; ++u) v[u] = cq[(size_t)s[u] * 32];
#pragma unroll
      for (int u = 0; u < 4; ++u) {
        acc.x = fmaf(w[u], v[u].x, acc.x);
        acc.y = fmaf(w[u], v[u].y, acc.y);
        acc.z = fmaf(w[u], v[u].z, acc.z);
        acc.w = fmaf(w[u], v[u].w, acc.w);
      }
    }
    for (; k + 2 <= cnt; k += 2) {
      int e = k + half;
      int s0 = __shfl(sv, e, 64);
      float w0 = __shfl(wv, e, 64);
      float4 v = cq[(size_t)s0 * 32];
      acc.x = fmaf(w0, v.x, acc.x);
      acc.y = fmaf(w0, v.y, acc.y);
      acc.z = fmaf(w0, v.z, acc.z);
      acc.w = fmaf(w0, v.w, acc.w);
    }
    if (k < cnt) {
      int s0 = __shfl(sv, k, 64);
      float w0 = __shfl(wv, k, 64);
      if (half == 0) {
        float4 v = cq[(size_t)s0 * 32];
        acc.x = fmaf(w0, v.x, acc.x);
        acc.y = fmaf(w0, v.y, acc.y);
        acc.z = fmaf(w0, v.z, acc.z);
        acc.w = fmaf(w0, v.w, acc.w);
      }
    }
  }
  acc.x += __shfl_xor(acc.x, 32, 64);
  acc.y += __shfl_xor(acc.y, 32, 64);
  acc.z += __shfl_xor(acc.z, 32, 64);
  acc.w += __shfl_xor(acc.w, 32, 64);
  return acc;
}

// layers 1,2: plain gather, write full row once.
__global__ __launch_bounds__(256) void k_gather(
    const float* __restrict__ cur, float* __restrict__ nxt,
    const int* __restrict__ off, const int2* __restrict__ rec, int N) {
  int n = blockIdx.x * 4 + (threadIdx.x >> 6);
  if (n >= N) return;
  int lane = threadIdx.x & 63;
  float4 acc = gather_row(cur, off, rec, n, lane);
  if (lane < 32) ((float4*)(nxt + (size_t)n * 128))[lane] = acc;
}

// layer 3 fused with expmap: h[n] = [expmap0(enc1) | expmap0(enc2)].
// Shifted store via lane shuffles (no LDS, no barrier). h aliases b1.
__global__ __launch_bounds__(256) void k_gather_exp(
    const float* __restrict__ cur, const float* b1, const float* __restrict__ b2,
    const int* __restrict__ off, const int2* __restrict__ rec,
    float* h, int N) {
  int n = blockIdx.x * 4 + (threadIdx.x >> 6);
  if (n >= N) return;
  int lane = threadIdx.x & 63;
  int q = lane & 31;
  float4 a3 = gather_row(cur, off, rec, n, lane);
  size_t b = (size_t)n * 128;
  float4 r1 = ((const float4*)(b1 + b))[q];
  float4 r2 = ((const float4*)(b2 + b))[q];
  float vv[4] = {a3.x + r1.x + r2.x, a3.y + r1.y + r2.y,
                 a3.z + r1.z + r2.z, a3.w + r1.w + r2.w};
  float p0 = 0.0f, p1 = 0.0f;
#pragma unroll
  for (int i = 0; i < 4; ++i) {
    int c = 4 * q + i;
    if (c < 63) p0 += vv[i] * vv[i]; else p1 += vv[i] * vv[i];
  }
  float ss0 = 0.5f * wsum(p0);         // halves hold duplicate copies
  float ss1 = 0.5f * wsum(p1);
  float nn0 = sqrtf(fmaxf(ss0, 1e-15f)), nn1 = sqrtf(fmaxf(ss1, 1e-15f));
  float s0 = sinhf(nn0) / nn0, s1 = sinhf(nn1) / nn1;
  int prev = (lane == 0) ? 0 : lane - 1;
  float pv2 = __shfl(vv[2], prev, 64);
  float pv3 = __shfl(vv[3], prev, 64);
  if (lane < 32) {
    float4 o;
    if (q < 16) {
      o.x = (q == 0) ? coshf(nn0) : s0 * pv3;
      o.y = s0 * vv[0]; o.z = s0 * vv[1]; o.w = s0 * vv[2];
    } else {
      o.x = (q == 16) ? coshf(nn1) : s1 * pv2;
      o.y = s1 * pv3; o.z = s1 * vv[0]; o.w = s1 * vv[1];
    }
    ((float4*)(h + b))[q] = o;
  }
}

// out[b] = min(dist2(.,.),50) + min(dist2(.,.),15); 4 pairs per wave.
__global__ __launch_bounds__(256) void k_score(
    const float* __restrict__ h, const int* __restrict__ idx,
    float* __restrict__ out, int B) {
  int w = blockIdx.x * 4 + (threadIdx.x >> 6);
  int lane = threadIdx.x & 63;
  int b0 = w * 4;
  if (b0 >= B) return;
  int np = min(4, B - b0);
  float2 hu[4], hv[4];
#pragma unroll
  for (int p = 0; p < 4; ++p) {
    int bb = b0 + ((p < np) ? p : 0);
    int u = idx[2 * bb], v = idx[2 * bb + 1];
    hu[p] = ((const float2*)(h + (size_t)u * 128))[lane];
    hv[p] = ((const float2*)(h + (size_t)v * 128))[lane];
  }
#pragma unroll
  for (int p = 0; p < 4; ++p) {
    if (p >= np) break;
    float px = hu[p].x * hv[p].x;
    if (lane == 0 || lane == 32) px = -px;   // time comps at cols 0 and 64
    float pp = px + hu[p].y * hv[p].y;
#pragma unroll
    for (int m = 1; m < 32; m <<= 1) pp += __shfl_xor(pp, m, 64);
    float dd = fmaxf(-pp, 1.0f + 1e-7f);
    float a = acoshf(dd);
    float s = fminf(a * a, (lane < 32) ? 50.0f : 15.0f);
    s += __shfl_xor(s, 32, 64);
    if (lane == 0) out[b0 + p] = s;
  }
}

extern "C" void kernel_launch(void* const* d_in, const int* in_sizes, int n_in,
                              void* d_out, int out_size, void* d_ws, size_t ws_size,
                              hipStream_t stream) {
  const float* emb = (const float*)d_in[0];
  const float* Tw  = (const float*)d_in[1];
  const float* ugr = (const float*)d_in[2];
  const float* sps = (const float*)d_in[3];
  const float* ew  = (const float*)d_in[4];
  const int* esrc  = (const int*)d_in[5];
  const int* edst  = (const int*)d_in[6];
  const int* idx   = (const int*)d_in[7];
  float* out = (float*)d_out;

  const int N    = in_sizes[0] / 64;   // 49152
  const int TAGS = in_sizes[1] / 64;   // 1024
  const int NU   = in_sizes[2] / 64;   // 8192
  const int NI   = in_sizes[3] / TAGS; // 40960
  const int E    = in_sizes[4];        // 1572864
  const int B    = in_sizes[7] / 2;    // 131072

  size_t rowsz = (size_t)N * 128 * sizeof(float);
  char* ws = (char*)d_ws;
  float* xt  = (float*)(ws);               // encoder layer-0 input
  float* b1  = (float*)(ws + rowsz);       // layer1 out; pb alias; h alias
  float* b2  = (float*)(ws + 2 * rowsz);   // layer2 out; stage alias
  float* gkg = (float*)(ws + 3 * rowsz);   // TAGS x 64
  size_t o = 3 * rowsz + (size_t)TAGS * 64 * sizeof(float);
  int* off   = (int*)(ws + o);  o += (size_t)(N + 1) * sizeof(int);
  int* bcur  = (int*)(ws + o);  o += (size_t)NBUK * sizeof(int);
  int* bbase = (int*)(ws + o);  o += (size_t)NBUK * sizeof(int);
  o = (o + 7) & ~(size_t)7;
  int2* rec = (int2*)(ws + o);             // E records (src, w)
  int2* stage = (int2*)b2;                 // NBUK x CAP staged records (13.6 MB)
  float* pb = b1;                          // KSPLIT x NI x 64 partials
  float* h  = b1;                          // final embeddings, in-place over b1

  // CSR build (no k_hist, no hierarchical scan, no per-dst global atomics)
  hipMemsetAsync(bcur, 0, (size_t)NBUK * sizeof(int), stream);
  k_passA<<<E / 2048, 256, 0, stream>>>(esrc, edst, ew, bcur, stage);
  k_bscan<<<1, 128, 0, stream>>>(bcur, bbase, off, N, E);
  k_passB2<<<NBUK, 256, 0, stream>>>(stage, bcur, bbase, off, rec);

  // feature prep (node + tag fused)
  k_prep<<<(N + TAGS + 3) / 4, 256, 0, stream>>>(emb, ugr, Tw, xt, gkg, N, NU, TAGS);
  dim3 hgrid(NI / 64, KSPLIT);
  k_hyper<<<hgrid, 256, 0, stream>>>(sps, gkg, pb, NI);
  k_combine<<<(NI + 3) / 4, 256, 0, stream>>>(pb, xt, NI, NU);

  // 3 encoder layers (gather-side, no atomics); layer 3 fused with expmap
  k_gather<<<(N + 3) / 4, 256, 0, stream>>>(xt, b1, off, rec, N);
  k_gather<<<(N + 3) / 4, 256, 0, stream>>>(b1, b2, off, rec, N);
  k_gather_exp<<<(N + 3) / 4, 256, 0, stream>>>(b2, b1, b2, off, rec, h, N);

  k_score<<<(B / 4 + 3) / 4, 256, 0, stream>>>(h, idx, out, B);
}

// Round 9
// 545.165 us; speedup vs baseline: 1.1598x; 1.0027x over previous
//
#include <hip/hip_runtime.h>

// TaxoRec forward pipeline on MI355X — round 9.
// Node feature rows padded to 128 f32 (512 B): cols 0..62 enc1, 63..125 enc2.
// CSR build fused: mega1 = passA (radix partition) || prep (node+tag maps);
// mega2 = passB2 (per-bucket offsets+scatter, self-computed bucket bases) ||
// hyper (K-split GEMM, direct-global sps reads + register prefetch).
// Gather: 16-edge unrolled loop (floored at ~3.6 TB/s random service rate).
// KSPLIT=2 so pb fits inside b1 (disjoint from stage=b2 during mega2).

#define KSPLIT 2
#define NBUK 96          // N / 512
#define CAP 18432        // bucket capacity; mean 16384, sigma 127 -> safe

__device__ __forceinline__ float wsum(float v) {
#pragma unroll
  for (int m = 32; m; m >>= 1) v += __shfl_xor(v, m, 64);
  return v;
}

__device__ __forceinline__ float logmap_scale(float ss) {
  float x0 = sqrtf(1.0f + ss);
  float alpha = fmaxf(x0, 1.0f + 1e-7f);
  float rnorm = sqrtf(fmaxf(ss, 1e-15f));
  return acoshf(alpha) / rnorm;
}

// ---- mega1: passA || prep ----------------------------------------------

__device__ void passA_body(
    const int* __restrict__ esrc, const int* __restrict__ edst,
    const float* __restrict__ ew, int* __restrict__ bcur,
    int2* __restrict__ stage, int bx) {
  __shared__ int lh[128];
  __shared__ int lscan[128];
  __shared__ int lcur[128];
  __shared__ int gb[128];
  __shared__ unsigned int keyb[2048];
  __shared__ float wvb[2048];
  int tid = threadIdx.x;
  int base = bx * 2048;
  if (tid < 128) lh[tid] = 0;
  __syncthreads();
  unsigned int key[8]; float wv[8];
#pragma unroll
  for (int r = 0; r < 8; ++r) {
    int e = base + r * 256 + tid;
    int d = edst[e];
    key[r] = ((unsigned int)d << 16) | (unsigned int)esrc[e];
    wv[r] = ew[e];
    atomicAdd(&lh[d >> 9], 1);
  }
  __syncthreads();
  if (tid < 128) lscan[tid] = lh[tid];
  __syncthreads();
  for (int d = 1; d < 128; d <<= 1) {
    int v = (tid < 128 && tid >= d) ? lscan[tid - d] : 0;
    __syncthreads();
    if (tid < 128) lscan[tid] += v;
    __syncthreads();
  }
  if (tid < 128) {
    int excl = lscan[tid] - lh[tid];
    lscan[tid] = excl;
    lcur[tid] = 0;
    if (tid < NBUK && lh[tid] > 0) {
      int rsv = atomicAdd(&bcur[tid], lh[tid]);
      gb[tid] = tid * CAP + rsv;
    }
  }
  __syncthreads();
#pragma unroll
  for (int r = 0; r < 8; ++r) {
    int b = key[r] >> 25;
    int lp = lscan[b] + atomicAdd(&lcur[b], 1);
    keyb[lp] = key[r];
    wvb[lp] = wv[r];
  }
  __syncthreads();
#pragma unroll
  for (int r = 0; r < 8; ++r) {
    int i = r * 256 + tid;
    unsigned int k2 = keyb[i];
    int b = k2 >> 25;
    stage[gb[b] + (i - lscan[b])] = make_int2((int)k2, __float_as_int(wvb[i]));
  }
}

__device__ void prep_body(
    const float* __restrict__ emb, const float* __restrict__ ugr,
    const float* __restrict__ Tw, float* __restrict__ xt,
    float* __restrict__ gkg, int N, int NU, int TAGS, int pbx) {
  int n = pbx * 4 + (threadIdx.x >> 6);
  int lane = threadIdx.x & 63;
  if (n < N) {
    size_t base = (size_t)n * 128;
    float r1 = (lane < 63) ? emb[(size_t)n * 64 + 1 + lane] : 0.0f;
    float sc1 = logmap_scale(wsum(r1 * r1));
    if (lane < 63) xt[base + lane] = sc1 * r1;
    if (lane == 63) { xt[base + 126] = 0.0f; xt[base + 127] = 0.0f; }
    if (n < NU) {
      float r2 = (lane < 63) ? ugr[(size_t)n * 64 + 1 + lane] : 0.0f;
      float sc2 = logmap_scale(wsum(r2 * r2));
      if (lane < 63) xt[base + 63 + lane] = sc2 * r2;
    }
  } else if (n < N + TAGS) {
    int t = n - N;
    float r = (lane < 63) ? Tw[(size_t)t * 64 + 1 + lane] : 0.0f;
    float ss = wsum(r * r);
    float x0 = sqrtf(1.0f + ss);
    float p = r / (x0 + 1.0f);          // l2p (sk = 1)
    float sp = wsum(p * p);
    float k = 2.0f * p / (1.0f + sp);   // p2k
    float sk2 = wsum(k * k);
    float gamma = 1.0f / sqrtf(fmaxf(1.0f - sk2, 1e-15f));
    gkg[(size_t)t * 64 + lane] = (lane < 63) ? gamma * k : gamma;
  }
}

__global__ __launch_bounds__(256) void k_mega1(
    const int* __restrict__ esrc, const int* __restrict__ edst,
    const float* __restrict__ ew, int* __restrict__ bcur,
    int2* __restrict__ stage,
    const float* __restrict__ emb, const float* __restrict__ ugr,
    const float* __restrict__ Tw, float* __restrict__ xt,
    float* __restrict__ gkg, int N, int NU, int TAGS, int nA) {
  if ((int)blockIdx.x < nA)
    passA_body(esrc, edst, ew, bcur, stage, blockIdx.x);
  else
    prep_body(emb, ugr, Tw, xt, gkg, N, NU, TAGS, blockIdx.x - nA);
}

// ---- mega2: passB2 || hyper --------------------------------------------

// per-bucket offsets + scatter; bucket base computed in-block (no k_bscan).
__device__ void passB2_body(
    const int2* __restrict__ stage, const int* __restrict__ bcur,
    int* __restrict__ off, int2* __restrict__ rec, int N, int E) {
  __shared__ int hist[512];
  __shared__ int pairs[256];
  __shared__ int cur[512];
  __shared__ int bs[128];
  int b = blockIdx.x, tid = threadIdx.x;
  if (tid < 128) bs[tid] = (tid < NBUK) ? min(bcur[tid], CAP) : 0;
  hist[tid] = 0; hist[tid + 256] = 0;
  __syncthreads();
  for (int d = 1; d < 128; d <<= 1) {
    int v = (tid < 128 && tid >= d) ? bs[tid - d] : 0;
    __syncthreads();
    if (tid < 128) bs[tid] += v;
    __syncthreads();
  }
  int cnt = min(bcur[b], CAP);
  int base = bs[b] - cnt;                 // exclusive bucket base
  if (b == 0 && tid == 0) off[N] = E;
  const int2* sg = stage + (size_t)b * CAP;
  for (int i = tid; i < cnt; i += 256)
    atomicAdd(&hist[((unsigned int)sg[i].x >> 16) & 511], 1);
  __syncthreads();
  int h0 = hist[2 * tid], h1 = hist[2 * tid + 1];
  int ps = h0 + h1;
  pairs[tid] = ps;
  __syncthreads();
  for (int d = 1; d < 256; d <<= 1) {
    int v = (tid >= d) ? pairs[tid - d] : 0;
    __syncthreads();
    pairs[tid] += v;
    __syncthreads();
  }
  int e0 = base + pairs[tid] - ps;        // exclusive prefix for dst 2*tid
  int e1 = e0 + h0;
  int gd = b * 512 + 2 * tid;
  off[gd] = e0;      cur[2 * tid] = e0;
  off[gd + 1] = e1;  cur[2 * tid + 1] = e1;
  __syncthreads();
  for (int i = tid; i < cnt; i += 256) {
    int2 r = sg[i];
    unsigned int k2 = (unsigned int)r.x;
    int d = (int)((k2 >> 16) & 511);
    int p = atomicAdd(&cur[d], 1);
    rec[p] = make_int2((int)(k2 & 0xFFFF), r.y);
  }
}

// hyper GEMM: 64 items x 64 dims per block, K = 1024/KSPLIT tags.
// sps read direct from global (2-deep register prefetch); g staged in LDS.
// Accumulation order identical to the verified staged version.
__device__ void hyper_body(
    const float* __restrict__ sps, const float* __restrict__ gkg,
    float* __restrict__ pb, int NI, int bx, int ksp) {
  __shared__ float g_tile[32 * 64];
  int tid = threadIdx.x;
  int tx = tid & 15, ty = tid >> 4;
  int gx = tid & 15, gy = tid >> 4;
  int ib = bx * 64;
  int kbase = ksp * (1024 / KSPLIT);
  float acc[4][4];
#pragma unroll
  for (int c = 0; c < 4; ++c)
#pragma unroll
    for (int d = 0; d < 4; ++d) acc[c][d] = 0.0f;

  const float4* sps4 = (const float4*)sps;
  const float4* gkg4 = (const float4*)gkg;
  size_t rb[4];
#pragma unroll
  for (int c = 0; c < 4; ++c) rb[c] = (size_t)(ib + ty * 4 + c) * 256;

  for (int kc = 0; kc < (1024 / KSPLIT) / 32; ++kc) {
#pragma unroll
    for (int r = 0; r < 2; ++r) {
      int grow = gy + 16 * r;
      *(float4*)&g_tile[grow * 64 + gx * 4] =
          gkg4[(size_t)(kbase + kc * 32 + grow) * 16 + gx];
    }
    __syncthreads();
    int t4 = (kbase >> 2) + kc * 8;
    float4 A[4], Nb[4];
#pragma unroll
    for (int c = 0; c < 4; ++c) A[c] = sps4[rb[c] + t4];
#pragma unroll
    for (int tg = 0; tg < 8; ++tg) {
#pragma unroll
      for (int c = 0; c < 4; ++c)
        if (tg < 7) Nb[c] = sps4[rb[c] + t4 + tg + 1];
      float4 g4[4];
#pragma unroll
      for (int j = 0; j < 4; ++j)
        g4[j] = *(const float4*)&g_tile[(tg * 4 + j) * 64 + tx * 4];
#pragma unroll
      for (int c = 0; c < 4; ++c) {
        float sv[4] = {A[c].x, A[c].y, A[c].z, A[c].w};
#pragma unroll
        for (int j = 0; j < 4; ++j) {
          acc[c][0] = fmaf(sv[j], g4[j].x, acc[c][0]);
          acc[c][1] = fmaf(sv[j], g4[j].y, acc[c][1]);
          acc[c][2] = fmaf(sv[j], g4[j].z, acc[c][2]);
          acc[c][3] = fmaf(sv[j], g4[j].w, acc[c][3]);
        }
      }
#pragma unroll
      for (int c = 0; c < 4; ++c)
        if (tg < 7) A[c] = Nb[c];
    }
    __syncthreads();
  }

  float* dst = pb + ((size_t)ksp * NI + ib) * 64;
#pragma unroll
  for (int c = 0; c < 4; ++c)
    *(float4*)&dst[(size_t)(ty * 4 + c) * 64 + tx * 4] =
        make_float4(acc[c][0], acc[c][1], acc[c][2], acc[c][3]);
}

__global__ __launch_bounds__(256) void k_mega2(
    const int2* __restrict__ stage, const int* __restrict__ bcur,
    int* __restrict__ off, int2* __restrict__ rec,
    const float* __restrict__ sps, const float* __restrict__ gkg,
    float* __restrict__ pb, int NI, int N, int E) {
  if ((int)blockIdx.x < NBUK) {
    passB2_body(stage, bcur, off, rec, N, E);
  } else {
    int hb = blockIdx.x - NBUK;
    int nbx = NI / 64;
    hyper_body(sps, gkg, pb, NI, hb % nbx, hb / nbx);
  }
}

// sum the KSPLIT partials, then k2p -> p2l -> logmap0; wave per item.
__global__ __launch_bounds__(256) void k_combine(
    const float* __restrict__ pb, float* __restrict__ xt, int NI, int NU) {
  int i = blockIdx.x * 4 + (threadIdx.x >> 6);
  if (i >= NI) return;
  int lane = threadIdx.x & 63;
  float v = 0.0f;
#pragma unroll
  for (int s = 0; s < KSPLIT; ++s) v += pb[((size_t)s * NI + i) * 64 + lane];
  float den = fmaxf(__shfl(v, 63, 64), 1e-15f);
  float y = v / den;
  float sy = wsum((lane < 63) ? y * y : 0.0f);
  float dk = 1.0f + sqrtf(fmaxf(1.0f - sy, 1e-15f));
  float q = y / dk;
  float nq = wsum((lane < 63) ? q * q : 0.0f);
  float f = 1.0f / (1.0f - nq + 1e-6f);
  float row0 = (1.0f + nq) * f;
  float r = 2.0f * q * f;
  float srr = wsum((lane < 63) ? r * r : 0.0f);
  float alpha = fmaxf(row0, 1.0f + 1e-7f);
  float scale = acoshf(alpha) / sqrtf(fmaxf(srr, 1e-15f));
  if (lane < 63)
    xt[(size_t)(NU + i) * 128 + 63 + lane] = scale * r;
}

// ---- gather core: 16 edges/iter, 8 row-loads in flight per half-wave ----
__device__ __forceinline__ float4 gather_row(
    const float* __restrict__ cur, const int* __restrict__ off,
    const int2* __restrict__ rec, int n, int lane) {
  int half = lane >> 5;
  int q = lane & 31;
  const float4* cq = (const float4*)cur + q;
  int beg = off[n], end = off[n + 1];
  float4 acc = make_float4(0.0f, 0.0f, 0.0f, 0.0f);
  for (int j = beg; j < end; j += 64) {
    int cnt = min(64, end - j);
    int sv = 0; float wv = 0.0f;
    if (lane < cnt) {
      int2 rc = rec[j + lane];
      sv = rc.x;
      wv = __int_as_float(rc.y);
    }
    int k = 0;
    for (; k + 16 <= cnt; k += 16) {
      int s[8]; float w[8]; float4 v[8];
#pragma unroll
      for (int u = 0; u < 8; ++u) {
        int e = k + 2 * u + half;
        s[u] = __shfl(sv, e, 64);
        w[u] = __shfl(wv, e, 64);
      }
#pragma unroll
      for (int u = 0; u < 8; ++u) v[u] = cq[(size_t)s[u] * 32];
#pragma unroll
      for (int u = 0; u < 8; ++u) {
        acc.x = fmaf(w[u], v[u].x, acc.x);
        acc.y = fmaf(w[u], v[u].y, acc.y);
        acc.z = fmaf(w[u], v[u].z, acc.z);
        acc.w = fmaf(w[u], v[u].w, acc.w);
      }
    }
    for (; k + 8 <= cnt; k += 8) {
      int s[4]; float w[4]; float4 v[4];
#pragma unroll
      for (int u = 0; u < 4; ++u) {
        int e = k + 2 * u + half;
        s[u] = __shfl(sv, e, 64);
        w[u] = __shfl(wv, e, 64);
      }
#pragma unroll
      for (int u = 0; u < 4; ++u) v[u] = cq[(size_t)s[u] * 32];
#pragma unroll
      for (int u = 0; u < 4; ++u) {
        acc.x = fmaf(w[u], v[u].x, acc.x);
        acc.y = fmaf(w[u], v[u].y, acc.y);
        acc.z = fmaf(w[u], v[u].z, acc.z);
        acc.w = fmaf(w[u], v[u].w, acc.w);
      }
    }
    for (; k + 2 <= cnt; k += 2) {
      int e = k + half;
      int s0 = __shfl(sv, e, 64);
      float w0 = __shfl(wv, e, 64);
      float4 v = cq[(size_t)s0 * 32];
      acc.x = fmaf(w0, v.x, acc.x);
      acc.y = fmaf(w0, v.y, acc.y);
      acc.z = fmaf(w0, v.z, acc.z);
      acc.w = fmaf(w0, v.w, acc.w);
    }
    if (k < cnt) {
      int s0 = __shfl(sv, k, 64);
      float w0 = __shfl(wv, k, 64);
      if (half == 0) {
        float4 v = cq[(size_t)s0 * 32];
        acc.x = fmaf(w0, v.x, acc.x);
        acc.y = fmaf(w0, v.y, acc.y);
        acc.z = fmaf(w0, v.z, acc.z);
        acc.w = fmaf(w0, v.w, acc.w);
      }
    }
  }
  acc.x += __shfl_xor(acc.x, 32, 64);
  acc.y += __shfl_xor(acc.y, 32, 64);
  acc.z += __shfl_xor(acc.z, 32, 64);
  acc.w += __shfl_xor(acc.w, 32, 64);
  return acc;
}

// layers 1,2: plain gather, write full row once.
__global__ __launch_bounds__(256) void k_gather(
    const float* __restrict__ cur, float* __restrict__ nxt,
    const int* __restrict__ off, const int2* __restrict__ rec, int N) {
  int n = blockIdx.x * 4 + (threadIdx.x >> 6);
  if (n >= N) return;
  int lane = threadIdx.x & 63;
  float4 acc = gather_row(cur, off, rec, n, lane);
  if (lane < 32) ((float4*)(nxt + (size_t)n * 128))[lane] = acc;
}

// layer 3 fused with expmap: h[n] = [expmap0(enc1) | expmap0(enc2)].
// Shifted store via lane shuffles (no LDS, no barrier). h aliases b1.
__global__ __launch_bounds__(256) void k_gather_exp(
    const float* __restrict__ cur, const float* b1, const float* __restrict__ b2,
    const int* __restrict__ off, const int2* __restrict__ rec,
    float* h, int N) {
  int n = blockIdx.x * 4 + (threadIdx.x >> 6);
  if (n >= N) return;
  int lane = threadIdx.x & 63;
  int q = lane & 31;
  float4 a3 = gather_row(cur, off, rec, n, lane);
  size_t b = (size_t)n * 128;
  float4 r1 = ((const float4*)(b1 + b))[q];
  float4 r2 = ((const float4*)(b2 + b))[q];
  float vv[4] = {a3.x + r1.x + r2.x, a3.y + r1.y + r2.y,
                 a3.z + r1.z + r2.z, a3.w + r1.w + r2.w};
  float p0 = 0.0f, p1 = 0.0f;
#pragma unroll
  for (int i = 0; i < 4; ++i) {
    int c = 4 * q + i;
    if (c < 63) p0 += vv[i] * vv[i]; else p1 += vv[i] * vv[i];
  }
  float ss0 = 0.5f * wsum(p0);         // halves hold duplicate copies
  float ss1 = 0.5f * wsum(p1);
  float nn0 = sqrtf(fmaxf(ss0, 1e-15f)), nn1 = sqrtf(fmaxf(ss1, 1e-15f));
  float s0 = sinhf(nn0) / nn0, s1 = sinhf(nn1) / nn1;
  int prev = (lane == 0) ? 0 : lane - 1;
  float pv2 = __shfl(vv[2], prev, 64);
  float pv3 = __shfl(vv[3], prev, 64);
  if (lane < 32) {
    float4 o;
    if (q < 16) {
      o.x = (q == 0) ? coshf(nn0) : s0 * pv3;
      o.y = s0 * vv[0]; o.z = s0 * vv[1]; o.w = s0 * vv[2];
    } else {
      o.x = (q == 16) ? coshf(nn1) : s1 * pv2;
      o.y = s1 * pv3; o.z = s1 * vv[0]; o.w = s1 * vv[1];
    }
    ((float4*)(h + b))[q] = o;
  }
}

// out[b] = min(dist2(.,.),50) + min(dist2(.,.),15); 4 pairs per wave.
__global__ __launch_bounds__(256) void k_score(
    const float* __restrict__ h, const int* __restrict__ idx,
    float* __restrict__ out, int B) {
  int w = blockIdx.x * 4 + (threadIdx.x >> 6);
  int lane = threadIdx.x & 63;
  int b0 = w * 4;
  if (b0 >= B) return;
  int np = min(4, B - b0);
  float2 hu[4], hv[4];
#pragma unroll
  for (int p = 0; p < 4; ++p) {
    int bb = b0 + ((p < np) ? p : 0);
    int u = idx[2 * bb], v = idx[2 * bb + 1];
    hu[p] = ((const float2*)(h + (size_t)u * 128))[lane];
    hv[p] = ((const float2*)(h + (size_t)v * 128))[lane];
  }
#pragma unroll
  for (int p = 0; p < 4; ++p) {
    if (p >= np) break;
    float px = hu[p].x * hv[p].x;
    if (lane == 0 || lane == 32) px = -px;   // time comps at cols 0 and 64
    float pp = px + hu[p].y * hv[p].y;
#pragma unroll
    for (int m = 1; m < 32; m <<= 1) pp += __shfl_xor(pp, m, 64);
    float dd = fmaxf(-pp, 1.0f + 1e-7f);
    float a = acoshf(dd);
    float s = fminf(a * a, (lane < 32) ? 50.0f : 15.0f);
    s += __shfl_xor(s, 32, 64);
    if (lane == 0) out[b0 + p] = s;
  }
}

extern "C" void kernel_launch(void* const* d_in, const int* in_sizes, int n_in,
                              void* d_out, int out_size, void* d_ws, size_t ws_size,
                              hipStream_t stream) {
  const float* emb = (const float*)d_in[0];
  const float* Tw  = (const float*)d_in[1];
  const float* ugr = (const float*)d_in[2];
  const float* sps = (const float*)d_in[3];
  const float* ew  = (const float*)d_in[4];
  const int* esrc  = (const int*)d_in[5];
  const int* edst  = (const int*)d_in[6];
  const int* idx   = (const int*)d_in[7];
  float* out = (float*)d_out;

  const int N    = in_sizes[0] / 64;   // 49152
  const int TAGS = in_sizes[1] / 64;   // 1024
  const int NU   = in_sizes[2] / 64;   // 8192
  const int NI   = in_sizes[3] / TAGS; // 40960
  const int E    = in_sizes[4];        // 1572864
  const int B    = in_sizes[7] / 2;    // 131072

  size_t rowsz = (size_t)N * 128 * sizeof(float);
  char* ws = (char*)d_ws;
  float* xt  = (float*)(ws);               // encoder layer-0 input
  float* b1  = (float*)(ws + rowsz);       // layer1 out; pb alias; h alias
  float* b2  = (float*)(ws + 2 * rowsz);   // layer2 out; stage alias
  float* gkg = (float*)(ws + 3 * rowsz);   // TAGS x 64
  size_t o = 3 * rowsz + (size_t)TAGS * 64 * sizeof(float);
  int* off   = (int*)(ws + o);  o += (size_t)(N + 1) * sizeof(int);
  int* bcur  = (int*)(ws + o);  o += (size_t)NBUK * sizeof(int);
  o = (o + 7) & ~(size_t)7;
  int2* rec = (int2*)(ws + o);             // E records (src, w)
  int2* stage = (int2*)b2;                 // NBUK x CAP staged records (14.2 MB)
  float* pb = b1;                          // KSPLIT x NI x 64 partials (21 MB,
                                           // fits b1 -> disjoint from stage)
  float* h  = b1;                          // final embeddings, in-place over b1

  const int nA = E / 2048;                 // 768 passA blocks
  const int nPrep = (N + TAGS + 3) / 4;    // 12544 prep blocks
  const int nHyper = (NI / 64) * KSPLIT;   // 1280 hyper blocks

  hipMemsetAsync(bcur, 0, (size_t)NBUK * sizeof(int), stream);
  // mega1: passA || prep (independent outputs)
  k_mega1<<<nA + nPrep, 256, 0, stream>>>(esrc, edst, ew, bcur, stage,
                                          emb, ugr, Tw, xt, gkg, N, NU, TAGS, nA);
  // mega2: passB2 (stage->rec/off) || hyper (sps,gkg->pb); disjoint buffers
  k_mega2<<<NBUK + nHyper, 256, 0, stream>>>(stage, bcur, off, rec,
                                             sps, gkg, pb, NI, N, E);
  k_combine<<<(NI + 3) / 4, 256, 0, stream>>>(pb, xt, NI, NU);

  // 3 encoder layers (gather-side); layer 3 fused with expmap
  k_gather<<<(N + 3) / 4, 256, 0, stream>>>(xt, b1, off, rec, N);
  k_gather<<<(N + 3) / 4, 256, 0, stream>>>(b1, b2, off, rec, N);
  k_gather_exp<<<(N + 3) / 4, 256, 0, stream>>>(b2, b1, b2, off, rec, h, N);

  k_score<<<(B / 4 + 3) / 4, 256, 0, stream>>>(h, idx, out, B);
}

// Round 10
// 539.433 us; speedup vs baseline: 1.1722x; 1.0106x over previous
//
#include <hip/hip_runtime.h>

// TaxoRec forward pipeline on MI355X — round 10.
// Node feature rows padded to 128 f32 (512 B): cols 0..62 enc1, 63..125 enc2.
// mega1 = passA (radix partition) || prep (node+tag maps).
// passB2: per-bucket offsets + scatter (bucket bases computed in-block).
// k_hyper: staged GEMM, 128 items x 64 dims/block, KSPLIT=4 (verified order),
// conflict-free LDS reads, coalesced staging. (Round-9 mega2 fusion reverted:
// direct-global sps reads were 16x redundant -> 180 us, VALU 24%.)
// Gather: 16-edge unrolled loop (floored at ~3.6 TB/s random service rate).

#define KSPLIT 4
#define NBUK 96          // N / 512
#define CAP 18432        // bucket capacity; mean 16384, sigma 127 -> safe

__device__ __forceinline__ float wsum(float v) {
#pragma unroll
  for (int m = 32; m; m >>= 1) v += __shfl_xor(v, m, 64);
  return v;
}

__device__ __forceinline__ float logmap_scale(float ss) {
  float x0 = sqrtf(1.0f + ss);
  float alpha = fmaxf(x0, 1.0f + 1e-7f);
  float rnorm = sqrtf(fmaxf(ss, 1e-15f));
  return acoshf(alpha) / rnorm;
}

// ---- mega1: passA || prep ----------------------------------------------

__device__ void passA_body(
    const int* __restrict__ esrc, const int* __restrict__ edst,
    const float* __restrict__ ew, int* __restrict__ bcur,
    int2* __restrict__ stage, int bx) {
  __shared__ int lh[128];
  __shared__ int lscan[128];
  __shared__ int lcur[128];
  __shared__ int gb[128];
  __shared__ unsigned int keyb[2048];
  __shared__ float wvb[2048];
  int tid = threadIdx.x;
  int base = bx * 2048;
  if (tid < 128) lh[tid] = 0;
  __syncthreads();
  unsigned int key[8]; float wv[8];
#pragma unroll
  for (int r = 0; r < 8; ++r) {
    int e = base + r * 256 + tid;
    int d = edst[e];
    key[r] = ((unsigned int)d << 16) | (unsigned int)esrc[e];
    wv[r] = ew[e];
    atomicAdd(&lh[d >> 9], 1);
  }
  __syncthreads();
  if (tid < 128) lscan[tid] = lh[tid];
  __syncthreads();
  for (int d = 1; d < 128; d <<= 1) {
    int v = (tid < 128 && tid >= d) ? lscan[tid - d] : 0;
    __syncthreads();
    if (tid < 128) lscan[tid] += v;
    __syncthreads();
  }
  if (tid < 128) {
    int excl = lscan[tid] - lh[tid];
    lscan[tid] = excl;
    lcur[tid] = 0;
    if (tid < NBUK && lh[tid] > 0) {
      int rsv = atomicAdd(&bcur[tid], lh[tid]);
      gb[tid] = tid * CAP + rsv;
    }
  }
  __syncthreads();
#pragma unroll
  for (int r = 0; r < 8; ++r) {
    int b = key[r] >> 25;
    int lp = lscan[b] + atomicAdd(&lcur[b], 1);
    keyb[lp] = key[r];
    wvb[lp] = wv[r];
  }
  __syncthreads();
#pragma unroll
  for (int r = 0; r < 8; ++r) {
    int i = r * 256 + tid;
    unsigned int k2 = keyb[i];
    int b = k2 >> 25;
    stage[gb[b] + (i - lscan[b])] = make_int2((int)k2, __float_as_int(wvb[i]));
  }
}

__device__ void prep_body(
    const float* __restrict__ emb, const float* __restrict__ ugr,
    const float* __restrict__ Tw, float* __restrict__ xt,
    float* __restrict__ gkg, int N, int NU, int TAGS, int pbx) {
  int n = pbx * 4 + (threadIdx.x >> 6);
  int lane = threadIdx.x & 63;
  if (n < N) {
    size_t base = (size_t)n * 128;
    float r1 = (lane < 63) ? emb[(size_t)n * 64 + 1 + lane] : 0.0f;
    float sc1 = logmap_scale(wsum(r1 * r1));
    if (lane < 63) xt[base + lane] = sc1 * r1;
    if (lane == 63) { xt[base + 126] = 0.0f; xt[base + 127] = 0.0f; }
    if (n < NU) {
      float r2 = (lane < 63) ? ugr[(size_t)n * 64 + 1 + lane] : 0.0f;
      float sc2 = logmap_scale(wsum(r2 * r2));
      if (lane < 63) xt[base + 63 + lane] = sc2 * r2;
    }
  } else if (n < N + TAGS) {
    int t = n - N;
    float r = (lane < 63) ? Tw[(size_t)t * 64 + 1 + lane] : 0.0f;
    float ss = wsum(r * r);
    float x0 = sqrtf(1.0f + ss);
    float p = r / (x0 + 1.0f);          // l2p (sk = 1)
    float sp = wsum(p * p);
    float k = 2.0f * p / (1.0f + sp);   // p2k
    float sk2 = wsum(k * k);
    float gamma = 1.0f / sqrtf(fmaxf(1.0f - sk2, 1e-15f));
    gkg[(size_t)t * 64 + lane] = (lane < 63) ? gamma * k : gamma;
  }
}

__global__ __launch_bounds__(256) void k_mega1(
    const int* __restrict__ esrc, const int* __restrict__ edst,
    const float* __restrict__ ew, int* __restrict__ bcur,
    int2* __restrict__ stage,
    const float* __restrict__ emb, const float* __restrict__ ugr,
    const float* __restrict__ Tw, float* __restrict__ xt,
    float* __restrict__ gkg, int N, int NU, int TAGS, int nA) {
  if ((int)blockIdx.x < nA)
    passA_body(esrc, edst, ew, bcur, stage, blockIdx.x);
  else
    prep_body(emb, ugr, Tw, xt, gkg, N, NU, TAGS, blockIdx.x - nA);
}

// ---- passB2: per-bucket offsets + scatter (self-computed bases) ----------

__global__ __launch_bounds__(256) void k_passB2(
    const int2* __restrict__ stage, const int* __restrict__ bcur,
    int* __restrict__ off, int2* __restrict__ rec, int N, int E) {
  __shared__ int hist[512];
  __shared__ int pairs[256];
  __shared__ int cur[512];
  __shared__ int bs[128];
  int b = blockIdx.x, tid = threadIdx.x;
  if (tid < 128) bs[tid] = (tid < NBUK) ? min(bcur[tid], CAP) : 0;
  hist[tid] = 0; hist[tid + 256] = 0;
  __syncthreads();
  for (int d = 1; d < 128; d <<= 1) {
    int v = (tid < 128 && tid >= d) ? bs[tid - d] : 0;
    __syncthreads();
    if (tid < 128) bs[tid] += v;
    __syncthreads();
  }
  int cnt = min(bcur[b], CAP);
  int base = bs[b] - cnt;                 // exclusive bucket base
  if (b == 0 && tid == 0) off[N] = E;
  const int2* sg = stage + (size_t)b * CAP;
  for (int i = tid; i < cnt; i += 256)
    atomicAdd(&hist[((unsigned int)sg[i].x >> 16) & 511], 1);
  __syncthreads();
  int h0 = hist[2 * tid], h1 = hist[2 * tid + 1];
  int ps = h0 + h1;
  pairs[tid] = ps;
  __syncthreads();
  for (int d = 1; d < 256; d <<= 1) {
    int v = (tid >= d) ? pairs[tid - d] : 0;
    __syncthreads();
    pairs[tid] += v;
    __syncthreads();
  }
  int e0 = base + pairs[tid] - ps;        // exclusive prefix for dst 2*tid
  int e1 = e0 + h0;
  int gd = b * 512 + 2 * tid;
  off[gd] = e0;      cur[2 * tid] = e0;
  off[gd + 1] = e1;  cur[2 * tid + 1] = e1;
  __syncthreads();
  for (int i = tid; i < cnt; i += 256) {
    int2 r = sg[i];
    unsigned int k2 = (unsigned int)r.x;
    int d = (int)((k2 >> 16) & 511);
    int p = atomicAdd(&cur[d], 1);
    rec[p] = make_int2((int)(k2 & 0xFFFF), r.y);
  }
}

// ---- hyper GEMM: 128 items x 64 dims per block, KSPLIT partials ----------
// Thread (tx=tid&15, ty=tid>>4) owns items {ty+16c : c<8}, dims tx*4..+4.
// s_tile[128][36]: ty-stride 36 floats -> banks 4 apart, conflict-free reads.
// Accumulation order per item identical to verified rounds 4-8.
__global__ __launch_bounds__(256) void k_hyper(
    const float* __restrict__ sps, const float* __restrict__ gkg,
    float* __restrict__ pb, int NI) {
  __shared__ float s_tile[128][36];
  __shared__ float g_tile[32][64];
  int tid = threadIdx.x;
  int tx = tid & 15, ty = tid >> 4;
  int sx = tid & 7,  sy = tid >> 3;   // s staging: 8 f4-cols x 32 rows
  int gx = tid & 15, gy = tid >> 4;   // g staging: 16 f4-cols x 16 rows
  int ib = blockIdx.x * 128;
  int kbase = blockIdx.y * 256;
  float acc[8][4];
#pragma unroll
  for (int c = 0; c < 8; ++c)
#pragma unroll
    for (int d = 0; d < 4; ++d) acc[c][d] = 0.0f;

  const float4* sps4 = (const float4*)sps;
  const float4* gkg4 = (const float4*)gkg;

  for (int kc = 0; kc < 8; ++kc) {    // 8 chunks of 32 tags
    int t4b = (kbase >> 2) + kc * 8;
#pragma unroll
    for (int r = 0; r < 4; ++r) {
      int row = sy + 32 * r;
      *(float4*)&s_tile[row][sx * 4] = sps4[(size_t)(ib + row) * 256 + t4b + sx];
    }
#pragma unroll
    for (int r = 0; r < 2; ++r) {
      int grow = gy + 16 * r;
      *(float4*)&g_tile[grow][gx * 4] =
          gkg4[(size_t)(kbase + kc * 32 + grow) * 16 + gx];
    }
    __syncthreads();
#pragma unroll
    for (int tg = 0; tg < 8; ++tg) {
      float4 g4[4];
#pragma unroll
      for (int j = 0; j < 4; ++j)
        g4[j] = *(const float4*)&g_tile[tg * 4 + j][tx * 4];
#pragma unroll
      for (int c = 0; c < 8; ++c) {
        float4 s4 = *(const float4*)&s_tile[ty + 16 * c][tg * 4];
        float sv[4] = {s4.x, s4.y, s4.z, s4.w};
#pragma unroll
        for (int j = 0; j < 4; ++j) {
          acc[c][0] = fmaf(sv[j], g4[j].x, acc[c][0]);
          acc[c][1] = fmaf(sv[j], g4[j].y, acc[c][1]);
          acc[c][2] = fmaf(sv[j], g4[j].z, acc[c][2]);
          acc[c][3] = fmaf(sv[j], g4[j].w, acc[c][3]);
        }
      }
    }
    __syncthreads();
  }

  float* dst = pb + ((size_t)blockIdx.y * NI + ib) * 64;
#pragma unroll
  for (int c = 0; c < 8; ++c)
    *(float4*)&dst[(size_t)(ty + 16 * c) * 64 + tx * 4] =
        make_float4(acc[c][0], acc[c][1], acc[c][2], acc[c][3]);
}

// sum the KSPLIT partials, then k2p -> p2l -> logmap0; wave per item.
__global__ __launch_bounds__(256) void k_combine(
    const float* __restrict__ pb, float* __restrict__ xt, int NI, int NU) {
  int i = blockIdx.x * 4 + (threadIdx.x >> 6);
  if (i >= NI) return;
  int lane = threadIdx.x & 63;
  float v = 0.0f;
#pragma unroll
  for (int s = 0; s < KSPLIT; ++s) v += pb[((size_t)s * NI + i) * 64 + lane];
  float den = fmaxf(__shfl(v, 63, 64), 1e-15f);
  float y = v / den;
  float sy = wsum((lane < 63) ? y * y : 0.0f);
  float dk = 1.0f + sqrtf(fmaxf(1.0f - sy, 1e-15f));
  float q = y / dk;
  float nq = wsum((lane < 63) ? q * q : 0.0f);
  float f = 1.0f / (1.0f - nq + 1e-6f);
  float row0 = (1.0f + nq) * f;
  float r = 2.0f * q * f;
  float srr = wsum((lane < 63) ? r * r : 0.0f);
  float alpha = fmaxf(row0, 1.0f + 1e-7f);
  float scale = acoshf(alpha) / sqrtf(fmaxf(srr, 1e-15f));
  if (lane < 63)
    xt[(size_t)(NU + i) * 128 + 63 + lane] = scale * r;
}

// ---- gather core: 16 edges/iter, 8 row-loads in flight per half-wave ----
__device__ __forceinline__ float4 gather_row(
    const float* __restrict__ cur, const int* __restrict__ off,
    const int2* __restrict__ rec, int n, int lane) {
  int half = lane >> 5;
  int q = lane & 31;
  const float4* cq = (const float4*)cur + q;
  int beg = off[n], end = off[n + 1];
  float4 acc = make_float4(0.0f, 0.0f, 0.0f, 0.0f);
  for (int j = beg; j < end; j += 64) {
    int cnt = min(64, end - j);
    int sv = 0; float wv = 0.0f;
    if (lane < cnt) {
      int2 rc = rec[j + lane];
      sv = rc.x;
      wv = __int_as_float(rc.y);
    }
    int k = 0;
    for (; k + 16 <= cnt; k += 16) {
      int s[8]; float w[8]; float4 v[8];
#pragma unroll
      for (int u = 0; u < 8; ++u) {
        int e = k + 2 * u + half;
        s[u] = __shfl(sv, e, 64);
        w[u] = __shfl(wv, e, 64);
      }
#pragma unroll
      for (int u = 0; u < 8; ++u) v[u] = cq[(size_t)s[u] * 32];
#pragma unroll
      for (int u = 0; u < 8; ++u) {
        acc.x = fmaf(w[u], v[u].x, acc.x);
        acc.y = fmaf(w[u], v[u].y, acc.y);
        acc.z = fmaf(w[u], v[u].z, acc.z);
        acc.w = fmaf(w[u], v[u].w, acc.w);
      }
    }
    for (; k + 8 <= cnt; k += 8) {
      int s[4]; float w[4]; float4 v[4];
#pragma unroll
      for (int u = 0; u < 4; ++u) {
        int e = k + 2 * u + half;
        s[u] = __shfl(sv, e, 64);
        w[u] = __shfl(wv, e, 64);
      }
#pragma unroll
      for (int u = 0; u < 4; ++u) v[u] = cq[(size_t)s[u] * 32];
#pragma unroll
      for (int u = 0; u < 4; ++u) {
        acc.x = fmaf(w[u], v[u].x, acc.x);
        acc.y = fmaf(w[u], v[u].y, acc.y);
        acc.z = fmaf(w[u], v[u].z, acc.z);
        acc.w = fmaf(w[u], v[u].w, acc.w);
      }
    }
    for (; k + 2 <= cnt; k += 2) {
      int e = k + half;
      int s0 = __shfl(sv, e, 64);
      float w0 = __shfl(wv, e, 64);
      float4 v = cq[(size_t)s0 * 32];
      acc.x = fmaf(w0, v.x, acc.x);
      acc.y = fmaf(w0, v.y, acc.y);
      acc.z = fmaf(w0, v.z, acc.z);
      acc.w = fmaf(w0, v.w, acc.w);
    }
    if (k < cnt) {
      int s0 = __shfl(sv, k, 64);
      float w0 = __shfl(wv, k, 64);
      if (half == 0) {
        float4 v = cq[(size_t)s0 * 32];
        acc.x = fmaf(w0, v.x, acc.x);
        acc.y = fmaf(w0, v.y, acc.y);
        acc.z = fmaf(w0, v.z, acc.z);
        acc.w = fmaf(w0, v.w, acc.w);
      }
    }
  }
  acc.x += __shfl_xor(acc.x, 32, 64);
  acc.y += __shfl_xor(acc.y, 32, 64);
  acc.z += __shfl_xor(acc.z, 32, 64);
  acc.w += __shfl_xor(acc.w, 32, 64);
  return acc;
}

// layers 1,2: plain gather, write full row once.
__global__ __launch_bounds__(256) void k_gather(
    const float* __restrict__ cur, float* __restrict__ nxt,
    const int* __restrict__ off, const int2* __restrict__ rec, int N) {
  int n = blockIdx.x * 4 + (threadIdx.x >> 6);
  if (n >= N) return;
  int lane = threadIdx.x & 63;
  float4 acc = gather_row(cur, off, rec, n, lane);
  if (lane < 32) ((float4*)(nxt + (size_t)n * 128))[lane] = acc;
}

// layer 3 fused with expmap: h[n] = [expmap0(enc1) | expmap0(enc2)].
// Shifted store via lane shuffles (no LDS, no barrier). h aliases b1.
__global__ __launch_bounds__(256) void k_gather_exp(
    const float* __restrict__ cur, const float* b1, const float* __restrict__ b2,
    const int* __restrict__ off, const int2* __restrict__ rec,
    float* h, int N) {
  int n = blockIdx.x * 4 + (threadIdx.x >> 6);
  if (n >= N) return;
  int lane = threadIdx.x & 63;
  int q = lane & 31;
  float4 a3 = gather_row(cur, off, rec, n, lane);
  size_t b = (size_t)n * 128;
  float4 r1 = ((const float4*)(b1 + b))[q];
  float4 r2 = ((const float4*)(b2 + b))[q];
  float vv[4] = {a3.x + r1.x + r2.x, a3.y + r1.y + r2.y,
                 a3.z + r1.z + r2.z, a3.w + r1.w + r2.w};
  float p0 = 0.0f, p1 = 0.0f;
#pragma unroll
  for (int i = 0; i < 4; ++i) {
    int c = 4 * q + i;
    if (c < 63) p0 += vv[i] * vv[i]; else p1 += vv[i] * vv[i];
  }
  float ss0 = 0.5f * wsum(p0);         // halves hold duplicate copies
  float ss1 = 0.5f * wsum(p1);
  float nn0 = sqrtf(fmaxf(ss0, 1e-15f)), nn1 = sqrtf(fmaxf(ss1, 1e-15f));
  float s0 = sinhf(nn0) / nn0, s1 = sinhf(nn1) / nn1;
  int prev = (lane == 0) ? 0 : lane - 1;
  float pv2 = __shfl(vv[2], prev, 64);
  float pv3 = __shfl(vv[3], prev, 64);
  if (lane < 32) {
    float4 o;
    if (q < 16) {
      o.x = (q == 0) ? coshf(nn0) : s0 * pv3;
      o.y = s0 * vv[0]; o.z = s0 * vv[1]; o.w = s0 * vv[2];
    } else {
      o.x = (q == 16) ? coshf(nn1) : s1 * pv2;
      o.y = s1 * pv3; o.z = s1 * vv[0]; o.w = s1 * vv[1];
    }
    ((float4*)(h + b))[q] = o;
  }
}

// out[b] = min(dist2(.,.),50) + min(dist2(.,.),15); 4 pairs per wave.
__global__ __launch_bounds__(256) void k_score(
    const float* __restrict__ h, const int* __restrict__ idx,
    float* __restrict__ out, int B) {
  int w = blockIdx.x * 4 + (threadIdx.x >> 6);
  int lane = threadIdx.x & 63;
  int b0 = w * 4;
  if (b0 >= B) return;
  int np = min(4, B - b0);
  float2 hu[4], hv[4];
#pragma unroll
  for (int p = 0; p < 4; ++p) {
    int bb = b0 + ((p < np) ? p : 0);
    int u = idx[2 * bb], v = idx[2 * bb + 1];
    hu[p] = ((const float2*)(h + (size_t)u * 128))[lane];
    hv[p] = ((const float2*)(h + (size_t)v * 128))[lane];
  }
#pragma unroll
  for (int p = 0; p < 4; ++p) {
    if (p >= np) break;
    float px = hu[p].x * hv[p].x;
    if (lane == 0 || lane == 32) px = -px;   // time comps at cols 0 and 64
    float pp = px + hu[p].y * hv[p].y;
#pragma unroll
    for (int m = 1; m < 32; m <<= 1) pp += __shfl_xor(pp, m, 64);
    float dd = fmaxf(-pp, 1.0f + 1e-7f);
    float a = acoshf(dd);
    float s = fminf(a * a, (lane < 32) ? 50.0f : 15.0f);
    s += __shfl_xor(s, 32, 64);
    if (lane == 0) out[b0 + p] = s;
  }
}

extern "C" void kernel_launch(void* const* d_in, const int* in_sizes, int n_in,
                              void* d_out, int out_size, void* d_ws, size_t ws_size,
                              hipStream_t stream) {
  const float* emb = (const float*)d_in[0];
  const float* Tw  = (const float*)d_in[1];
  const float* ugr = (const float*)d_in[2];
  const float* sps = (const float*)d_in[3];
  const float* ew  = (const float*)d_in[4];
  const int* esrc  = (const int*)d_in[5];
  const int* edst  = (const int*)d_in[6];
  const int* idx   = (const int*)d_in[7];
  float* out = (float*)d_out;

  const int N    = in_sizes[0] / 64;   // 49152
  const int TAGS = in_sizes[1] / 64;   // 1024
  const int NU   = in_sizes[2] / 64;   // 8192
  const int NI   = in_sizes[3] / TAGS; // 40960
  const int E    = in_sizes[4];        // 1572864
  const int B    = in_sizes[7] / 2;    // 131072

  size_t rowsz = (size_t)N * 128 * sizeof(float);
  char* ws = (char*)d_ws;
  float* xt  = (float*)(ws);               // encoder layer-0 input
  float* b1  = (float*)(ws + rowsz);       // layer1 out; pb alias; h alias
  float* b2  = (float*)(ws + 2 * rowsz);   // layer2 out; stage alias
  float* gkg = (float*)(ws + 3 * rowsz);   // TAGS x 64
  size_t o = 3 * rowsz + (size_t)TAGS * 64 * sizeof(float);
  int* off   = (int*)(ws + o);  o += (size_t)(N + 1) * sizeof(int);
  int* bcur  = (int*)(ws + o);  o += (size_t)NBUK * sizeof(int);
  o = (o + 7) & ~(size_t)7;
  int2* rec = (int2*)(ws + o);             // E records (src, w)
  int2* stage = (int2*)b2;                 // NBUK x CAP staged records (14.2 MB)
  float* pb = b1;                          // KSPLIT x NI x 64 partials (42 MB:
                                           // b1 + first 16.8 MB of b2; stage is
                                           // consumed by passB2 before hyper)
  float* h  = b1;                          // final embeddings, in-place over b1

  const int nA = E / 2048;                 // 768 passA blocks
  const int nPrep = (N + TAGS + 3) / 4;    // prep blocks

  hipMemsetAsync(bcur, 0, (size_t)NBUK * sizeof(int), stream);
  // mega1: passA || prep (independent outputs)
  k_mega1<<<nA + nPrep, 256, 0, stream>>>(esrc, edst, ew, bcur, stage,
                                          emb, ugr, Tw, xt, gkg, N, NU, TAGS, nA);
  // passB2 consumes stage -> rec/off (before hyper overwrites that region)
  k_passB2<<<NBUK, 256, 0, stream>>>(stage, bcur, off, rec, N, E);
  // hyper GEMM -> pb partials, then combine -> xt item rows
  dim3 hgrid(NI / 128, KSPLIT);
  k_hyper<<<hgrid, 256, 0, stream>>>(sps, gkg, pb, NI);
  k_combine<<<(NI + 3) / 4, 256, 0, stream>>>(pb, xt, NI, NU);

  // 3 encoder layers (gather-side); layer 3 fused with expmap
  k_gather<<<(N + 3) / 4, 256, 0, stream>>>(xt, b1, off, rec, N);
  k_gather<<<(N + 3) / 4, 256, 0, stream>>>(b1, b2, off, rec, N);
  k_gather_exp<<<(N + 3) / 4, 256, 0, stream>>>(b2, b1, b2, off, rec, h, N);

  k_score<<<(B / 4 + 3) / 4, 256, 0, stream>>>(h, idx, out, B);
}

// Round 11
// 505.188 us; speedup vs baseline: 1.2516x; 1.0678x over previous
//
#include <hip/hip_runtime.h>

// TaxoRec forward pipeline on MI355X — round 11.
// Node feature rows padded to 128 f32 (512 B): cols 0..62 enc1, 63..125 enc2.
// mega1 = passA (radix partition) || prep (node+tag maps).
// mega2 = passB2 (per-bucket offsets+scatter) || hyper (STAGED 128x64 GEMM,
// KSPLIT=2 so pb fits in b1, disjoint from stage=b2). Round-9's fusion
// failure was the direct-global sps pattern, not the fusion; hyper here keeps
// the verified coalesced staging.
// Gather: 16-edge unrolled loop (floored at ~3.6 TB/s random service rate).

#define KSPLIT 2
#define NBUK 96          // N / 512
#define CAP 18432        // bucket capacity; mean 16384, sigma 127 -> safe

__device__ __forceinline__ float wsum(float v) {
#pragma unroll
  for (int m = 32; m; m >>= 1) v += __shfl_xor(v, m, 64);
  return v;
}

__device__ __forceinline__ float logmap_scale(float ss) {
  float x0 = sqrtf(1.0f + ss);
  float alpha = fmaxf(x0, 1.0f + 1e-7f);
  float rnorm = sqrtf(fmaxf(ss, 1e-15f));
  return acoshf(alpha) / rnorm;
}

// ---- mega1: passA || prep ----------------------------------------------

__device__ void passA_body(
    const int* __restrict__ esrc, const int* __restrict__ edst,
    const float* __restrict__ ew, int* __restrict__ bcur,
    int2* __restrict__ stage, int bx) {
  __shared__ int lh[128];
  __shared__ int lscan[128];
  __shared__ int lcur[128];
  __shared__ int gb[128];
  __shared__ unsigned int keyb[2048];
  __shared__ float wvb[2048];
  int tid = threadIdx.x;
  int base = bx * 2048;
  if (tid < 128) lh[tid] = 0;
  __syncthreads();
  unsigned int key[8]; float wv[8];
#pragma unroll
  for (int r = 0; r < 8; ++r) {
    int e = base + r * 256 + tid;
    int d = edst[e];
    key[r] = ((unsigned int)d << 16) | (unsigned int)esrc[e];
    wv[r] = ew[e];
    atomicAdd(&lh[d >> 9], 1);
  }
  __syncthreads();
  if (tid < 128) lscan[tid] = lh[tid];
  __syncthreads();
  for (int d = 1; d < 128; d <<= 1) {
    int v = (tid < 128 && tid >= d) ? lscan[tid - d] : 0;
    __syncthreads();
    if (tid < 128) lscan[tid] += v;
    __syncthreads();
  }
  if (tid < 128) {
    int excl = lscan[tid] - lh[tid];
    lscan[tid] = excl;
    lcur[tid] = 0;
    if (tid < NBUK && lh[tid] > 0) {
      int rsv = atomicAdd(&bcur[tid], lh[tid]);
      gb[tid] = tid * CAP + rsv;
    }
  }
  __syncthreads();
#pragma unroll
  for (int r = 0; r < 8; ++r) {
    int b = key[r] >> 25;
    int lp = lscan[b] + atomicAdd(&lcur[b], 1);
    keyb[lp] = key[r];
    wvb[lp] = wv[r];
  }
  __syncthreads();
#pragma unroll
  for (int r = 0; r < 8; ++r) {
    int i = r * 256 + tid;
    unsigned int k2 = keyb[i];
    int b = k2 >> 25;
    stage[gb[b] + (i - lscan[b])] = make_int2((int)k2, __float_as_int(wvb[i]));
  }
}

__device__ void prep_body(
    const float* __restrict__ emb, const float* __restrict__ ugr,
    const float* __restrict__ Tw, float* __restrict__ xt,
    float* __restrict__ gkg, int N, int NU, int TAGS, int pbx) {
  int n = pbx * 4 + (threadIdx.x >> 6);
  int lane = threadIdx.x & 63;
  if (n < N) {
    size_t base = (size_t)n * 128;
    float r1 = (lane < 63) ? emb[(size_t)n * 64 + 1 + lane] : 0.0f;
    float sc1 = logmap_scale(wsum(r1 * r1));
    if (lane < 63) xt[base + lane] = sc1 * r1;
    if (lane == 63) { xt[base + 126] = 0.0f; xt[base + 127] = 0.0f; }
    if (n < NU) {
      float r2 = (lane < 63) ? ugr[(size_t)n * 64 + 1 + lane] : 0.0f;
      float sc2 = logmap_scale(wsum(r2 * r2));
      if (lane < 63) xt[base + 63 + lane] = sc2 * r2;
    }
  } else if (n < N + TAGS) {
    int t = n - N;
    float r = (lane < 63) ? Tw[(size_t)t * 64 + 1 + lane] : 0.0f;
    float ss = wsum(r * r);
    float x0 = sqrtf(1.0f + ss);
    float p = r / (x0 + 1.0f);          // l2p (sk = 1)
    float sp = wsum(p * p);
    float k = 2.0f * p / (1.0f + sp);   // p2k
    float sk2 = wsum(k * k);
    float gamma = 1.0f / sqrtf(fmaxf(1.0f - sk2, 1e-15f));
    gkg[(size_t)t * 64 + lane] = (lane < 63) ? gamma * k : gamma;
  }
}

__global__ __launch_bounds__(256) void k_mega1(
    const int* __restrict__ esrc, const int* __restrict__ edst,
    const float* __restrict__ ew, int* __restrict__ bcur,
    int2* __restrict__ stage,
    const float* __restrict__ emb, const float* __restrict__ ugr,
    const float* __restrict__ Tw, float* __restrict__ xt,
    float* __restrict__ gkg, int N, int NU, int TAGS, int nA) {
  if ((int)blockIdx.x < nA)
    passA_body(esrc, edst, ew, bcur, stage, blockIdx.x);
  else
    prep_body(emb, ugr, Tw, xt, gkg, N, NU, TAGS, blockIdx.x - nA);
}

// ---- mega2: passB2 || hyper (staged, verified load pattern) --------------

__device__ void passB2_body(
    const int2* __restrict__ stage, const int* __restrict__ bcur,
    int* __restrict__ off, int2* __restrict__ rec, int N, int E) {
  __shared__ int hist[512];
  __shared__ int pairs[256];
  __shared__ int cur[512];
  __shared__ int bs[128];
  int b = blockIdx.x, tid = threadIdx.x;
  if (tid < 128) bs[tid] = (tid < NBUK) ? min(bcur[tid], CAP) : 0;
  hist[tid] = 0; hist[tid + 256] = 0;
  __syncthreads();
  for (int d = 1; d < 128; d <<= 1) {
    int v = (tid < 128 && tid >= d) ? bs[tid - d] : 0;
    __syncthreads();
    if (tid < 128) bs[tid] += v;
    __syncthreads();
  }
  int cnt = min(bcur[b], CAP);
  int base = bs[b] - cnt;                 // exclusive bucket base
  if (b == 0 && tid == 0) off[N] = E;
  const int2* sg = stage + (size_t)b * CAP;
  for (int i = tid; i < cnt; i += 256)
    atomicAdd(&hist[((unsigned int)sg[i].x >> 16) & 511], 1);
  __syncthreads();
  int h0 = hist[2 * tid], h1 = hist[2 * tid + 1];
  int ps = h0 + h1;
  pairs[tid] = ps;
  __syncthreads();
  for (int d = 1; d < 256; d <<= 1) {
    int v = (tid >= d) ? pairs[tid - d] : 0;
    __syncthreads();
    pairs[tid] += v;
    __syncthreads();
  }
  int e0 = base + pairs[tid] - ps;        // exclusive prefix for dst 2*tid
  int e1 = e0 + h0;
  int gd = b * 512 + 2 * tid;
  off[gd] = e0;      cur[2 * tid] = e0;
  off[gd + 1] = e1;  cur[2 * tid + 1] = e1;
  __syncthreads();
  for (int i = tid; i < cnt; i += 256) {
    int2 r = sg[i];
    unsigned int k2 = (unsigned int)r.x;
    int d = (int)((k2 >> 16) & 511);
    int p = atomicAdd(&cur[d], 1);
    rec[p] = make_int2((int)(k2 & 0xFFFF), r.y);
  }
}

// hyper GEMM: 128 items x 64 dims per block, K = 1024/KSPLIT tags.
// Staged coalesced sps + gkg tiles; conflict-free LDS reads (stride 36).
// Accumulation order per item identical to verified rounds 4-10.
__device__ void hyper_body(
    const float* __restrict__ sps, const float* __restrict__ gkg,
    float* __restrict__ pb, int NI, int bx, int ksp) {
  __shared__ float s_tile[128][36];
  __shared__ float g_tile[32][64];
  int tid = threadIdx.x;
  int tx = tid & 15, ty = tid >> 4;
  int sx = tid & 7,  sy = tid >> 3;   // s staging: 8 f4-cols x 32 rows
  int gx = tid & 15, gy = tid >> 4;   // g staging: 16 f4-cols x 16 rows
  int ib = bx * 128;
  int kbase = ksp * (1024 / KSPLIT);
  float acc[8][4];
#pragma unroll
  for (int c = 0; c < 8; ++c)
#pragma unroll
    for (int d = 0; d < 4; ++d) acc[c][d] = 0.0f;

  const float4* sps4 = (const float4*)sps;
  const float4* gkg4 = (const float4*)gkg;

  for (int kc = 0; kc < (1024 / KSPLIT) / 32; ++kc) {   // chunks of 32 tags
    int t4b = (kbase >> 2) + kc * 8;
#pragma unroll
    for (int r = 0; r < 4; ++r) {
      int row = sy + 32 * r;
      *(float4*)&s_tile[row][sx * 4] = sps4[(size_t)(ib + row) * 256 + t4b + sx];
    }
#pragma unroll
    for (int r = 0; r < 2; ++r) {
      int grow = gy + 16 * r;
      *(float4*)&g_tile[grow][gx * 4] =
          gkg4[(size_t)(kbase + kc * 32 + grow) * 16 + gx];
    }
    __syncthreads();
#pragma unroll
    for (int tg = 0; tg < 8; ++tg) {
      float4 g4[4];
#pragma unroll
      for (int j = 0; j < 4; ++j)
        g4[j] = *(const float4*)&g_tile[tg * 4 + j][tx * 4];
#pragma unroll
      for (int c = 0; c < 8; ++c) {
        float4 s4 = *(const float4*)&s_tile[ty + 16 * c][tg * 4];
        float sv[4] = {s4.x, s4.y, s4.z, s4.w};
#pragma unroll
        for (int j = 0; j < 4; ++j) {
          acc[c][0] = fmaf(sv[j], g4[j].x, acc[c][0]);
          acc[c][1] = fmaf(sv[j], g4[j].y, acc[c][1]);
          acc[c][2] = fmaf(sv[j], g4[j].z, acc[c][2]);
          acc[c][3] = fmaf(sv[j], g4[j].w, acc[c][3]);
        }
      }
    }
    __syncthreads();
  }

  float* dst = pb + ((size_t)ksp * NI + ib) * 64;
#pragma unroll
  for (int c = 0; c < 8; ++c)
    *(float4*)&dst[(size_t)(ty + 16 * c) * 64 + tx * 4] =
        make_float4(acc[c][0], acc[c][1], acc[c][2], acc[c][3]);
}

__global__ __launch_bounds__(256) void k_mega2(
    const int2* __restrict__ stage, const int* __restrict__ bcur,
    int* __restrict__ off, int2* __restrict__ rec,
    const float* __restrict__ sps, const float* __restrict__ gkg,
    float* __restrict__ pb, int NI, int N, int E) {
  if ((int)blockIdx.x < NBUK) {
    passB2_body(stage, bcur, off, rec, N, E);
  } else {
    int hb = blockIdx.x - NBUK;
    int nbx = NI / 128;
    hyper_body(sps, gkg, pb, NI, hb % nbx, hb / nbx);
  }
}

// sum the KSPLIT partials, then k2p -> p2l -> logmap0; wave per item.
__global__ __launch_bounds__(256) void k_combine(
    const float* __restrict__ pb, float* __restrict__ xt, int NI, int NU) {
  int i = blockIdx.x * 4 + (threadIdx.x >> 6);
  if (i >= NI) return;
  int lane = threadIdx.x & 63;
  float v = 0.0f;
#pragma unroll
  for (int s = 0; s < KSPLIT; ++s) v += pb[((size_t)s * NI + i) * 64 + lane];
  float den = fmaxf(__shfl(v, 63, 64), 1e-15f);
  float y = v / den;
  float sy = wsum((lane < 63) ? y * y : 0.0f);
  float dk = 1.0f + sqrtf(fmaxf(1.0f - sy, 1e-15f));
  float q = y / dk;
  float nq = wsum((lane < 63) ? q * q : 0.0f);
  float f = 1.0f / (1.0f - nq + 1e-6f);
  float row0 = (1.0f + nq) * f;
  float r = 2.0f * q * f;
  float srr = wsum((lane < 63) ? r * r : 0.0f);
  float alpha = fmaxf(row0, 1.0f + 1e-7f);
  float scale = acoshf(alpha) / sqrtf(fmaxf(srr, 1e-15f));
  if (lane < 63)
    xt[(size_t)(NU + i) * 128 + 63 + lane] = scale * r;
}

// ---- gather core: 16 edges/iter, 8 row-loads in flight per half-wave ----
__device__ __forceinline__ float4 gather_row(
    const float* __restrict__ cur, const int* __restrict__ off,
    const int2* __restrict__ rec, int n, int lane) {
  int half = lane >> 5;
  int q = lane & 31;
  const float4* cq = (const float4*)cur + q;
  int beg = off[n], end = off[n + 1];
  float4 acc = make_float4(0.0f, 0.0f, 0.0f, 0.0f);
  for (int j = beg; j < end; j += 64) {
    int cnt = min(64, end - j);
    int sv = 0; float wv = 0.0f;
    if (lane < cnt) {
      int2 rc = rec[j + lane];
      sv = rc.x;
      wv = __int_as_float(rc.y);
    }
    int k = 0;
    for (; k + 16 <= cnt; k += 16) {
      int s[8]; float w[8]; float4 v[8];
#pragma unroll
      for (int u = 0; u < 8; ++u) {
        int e = k + 2 * u + half;
        s[u] = __shfl(sv, e, 64);
        w[u] = __shfl(wv, e, 64);
      }
#pragma unroll
      for (int u = 0; u < 8; ++u) v[u] = cq[(size_t)s[u] * 32];
#pragma unroll
      for (int u = 0; u < 8; ++u) {
        acc.x = fmaf(w[u], v[u].x, acc.x);
        acc.y = fmaf(w[u], v[u].y, acc.y);
        acc.z = fmaf(w[u], v[u].z, acc.z);
        acc.w = fmaf(w[u], v[u].w, acc.w);
      }
    }
    for (; k + 8 <= cnt; k += 8) {
      int s[4]; float w[4]; float4 v[4];
#pragma unroll
      for (int u = 0; u < 4; ++u) {
        int e = k + 2 * u + half;
        s[u] = __shfl(sv, e, 64);
        w[u] = __shfl(wv, e, 64);
      }
#pragma unroll
      for (int u = 0; u < 4; ++u) v[u] = cq[(size_t)s[u] * 32];
#pragma unroll
      for (int u = 0; u < 4; ++u) {
        acc.x = fmaf(w[u], v[u].x, acc.x);
        acc.y = fmaf(w[u], v[u].y, acc.y);
        acc.z = fmaf(w[u], v[u].z, acc.z);
        acc.w = fmaf(w[u], v[u].w, acc.w);
      }
    }
    for (; k + 2 <= cnt; k += 2) {
      int e = k + half;
      int s0 = __shfl(sv, e, 64);
      float w0 = __shfl(wv, e, 64);
      float4 v = cq[(size_t)s0 * 32];
      acc.x = fmaf(w0, v.x, acc.x);
      acc.y = fmaf(w0, v.y, acc.y);
      acc.z = fmaf(w0, v.z, acc.z);
      acc.w = fmaf(w0, v.w, acc.w);
    }
    if (k < cnt) {
      int s0 = __shfl(sv, k, 64);
      float w0 = __shfl(wv, k, 64);
      if (half == 0) {
        float4 v = cq[(size_t)s0 * 32];
        acc.x = fmaf(w0, v.x, acc.x);
        acc.y = fmaf(w0, v.y, acc.y);
        acc.z = fmaf(w0, v.z, acc.z);
        acc.w = fmaf(w0, v.w, acc.w);
      }
    }
  }
  acc.x += __shfl_xor(acc.x, 32, 64);
  acc.y += __shfl_xor(acc.y, 32, 64);
  acc.z += __shfl_xor(acc.z, 32, 64);
  acc.w += __shfl_xor(acc.w, 32, 64);
  return acc;
}

// layers 1,2: plain gather, write full row once.
__global__ __launch_bounds__(256) void k_gather(
    const float* __restrict__ cur, float* __restrict__ nxt,
    const int* __restrict__ off, const int2* __restrict__ rec, int N) {
  int n = blockIdx.x * 4 + (threadIdx.x >> 6);
  if (n >= N) return;
  int lane = threadIdx.x & 63;
  float4 acc = gather_row(cur, off, rec, n, lane);
  if (lane < 32) ((float4*)(nxt + (size_t)n * 128))[lane] = acc;
}

// layer 3 fused with expmap: h[n] = [expmap0(enc1) | expmap0(enc2)].
// Shifted store via lane shuffles (no LDS, no barrier). h aliases b1.
__global__ __launch_bounds__(256) void k_gather_exp(
    const float* __restrict__ cur, const float* b1, const float* __restrict__ b2,
    const int* __restrict__ off, const int2* __restrict__ rec,
    float* h, int N) {
  int n = blockIdx.x * 4 + (threadIdx.x >> 6);
  if (n >= N) return;
  int lane = threadIdx.x & 63;
  int q = lane & 31;
  float4 a3 = gather_row(cur, off, rec, n, lane);
  size_t b = (size_t)n * 128;
  float4 r1 = ((const float4*)(b1 + b))[q];
  float4 r2 = ((const float4*)(b2 + b))[q];
  float vv[4] = {a3.x + r1.x + r2.x, a3.y + r1.y + r2.y,
                 a3.z + r1.z + r2.z, a3.w + r1.w + r2.w};
  float p0 = 0.0f, p1 = 0.0f;
#pragma unroll
  for (int i = 0; i < 4; ++i) {
    int c = 4 * q + i;
    if (c < 63) p0 += vv[i] * vv[i]; else p1 += vv[i] * vv[i];
  }
  float ss0 = 0.5f * wsum(p0);         // halves hold duplicate copies
  float ss1 = 0.5f * wsum(p1);
  float nn0 = sqrtf(fmaxf(ss0, 1e-15f)), nn1 = sqrtf(fmaxf(ss1, 1e-15f));
  float s0 = sinhf(nn0) / nn0, s1 = sinhf(nn1) / nn1;
  int prev = (lane == 0) ? 0 : lane - 1;
  float pv2 = __shfl(vv[2], prev, 64);
  float pv3 = __shfl(vv[3], prev, 64);
  if (lane < 32) {
    float4 o;
    if (q < 16) {
      o.x = (q == 0) ? coshf(nn0) : s0 * pv3;
      o.y = s0 * vv[0]; o.z = s0 * vv[1]; o.w = s0 * vv[2];
    } else {
      o.x = (q == 16) ? coshf(nn1) : s1 * pv2;
      o.y = s1 * pv3; o.z = s1 * vv[0]; o.w = s1 * vv[1];
    }
    ((float4*)(h + b))[q] = o;
  }
}

// out[b] = min(dist2(.,.),50) + min(dist2(.,.),15); 4 pairs per wave.
__global__ __launch_bounds__(256) void k_score(
    const float* __restrict__ h, const int* __restrict__ idx,
    float* __restrict__ out, int B) {
  int w = blockIdx.x * 4 + (threadIdx.x >> 6);
  int lane = threadIdx.x & 63;
  int b0 = w * 4;
  if (b0 >= B) return;
  int np = min(4, B - b0);
  float2 hu[4], hv[4];
#pragma unroll
  for (int p = 0; p < 4; ++p) {
    int bb = b0 + ((p < np) ? p : 0);
    int u = idx[2 * bb], v = idx[2 * bb + 1];
    hu[p] = ((const float2*)(h + (size_t)u * 128))[lane];
    hv[p] = ((const float2*)(h + (size_t)v * 128))[lane];
  }
#pragma unroll
  for (int p = 0; p < 4; ++p) {
    if (p >= np) break;
    float px = hu[p].x * hv[p].x;
    if (lane == 0 || lane == 32) px = -px;   // time comps at cols 0 and 64
    float pp = px + hu[p].y * hv[p].y;
#pragma unroll
    for (int m = 1; m < 32; m <<= 1) pp += __shfl_xor(pp, m, 64);
    float dd = fmaxf(-pp, 1.0f + 1e-7f);
    float a = acoshf(dd);
    float s = fminf(a * a, (lane < 32) ? 50.0f : 15.0f);
    s += __shfl_xor(s, 32, 64);
    if (lane == 0) out[b0 + p] = s;
  }
}

extern "C" void kernel_launch(void* const* d_in, const int* in_sizes, int n_in,
                              void* d_out, int out_size, void* d_ws, size_t ws_size,
                              hipStream_t stream) {
  const float* emb = (const float*)d_in[0];
  const float* Tw  = (const float*)d_in[1];
  const float* ugr = (const float*)d_in[2];
  const float* sps = (const float*)d_in[3];
  const float* ew  = (const float*)d_in[4];
  const int* esrc  = (const int*)d_in[5];
  const int* edst  = (const int*)d_in[6];
  const int* idx   = (const int*)d_in[7];
  float* out = (float*)d_out;

  const int N    = in_sizes[0] / 64;   // 49152
  const int TAGS = in_sizes[1] / 64;   // 1024
  const int NU   = in_sizes[2] / 64;   // 8192
  const int NI   = in_sizes[3] / TAGS; // 40960
  const int E    = in_sizes[4];        // 1572864
  const int B    = in_sizes[7] / 2;    // 131072

  size_t rowsz = (size_t)N * 128 * sizeof(float);
  char* ws = (char*)d_ws;
  float* xt  = (float*)(ws);               // encoder layer-0 input
  float* b1  = (float*)(ws + rowsz);       // layer1 out; pb alias; h alias
  float* b2  = (float*)(ws + 2 * rowsz);   // layer2 out; stage alias
  float* gkg = (float*)(ws + 3 * rowsz);   // TAGS x 64
  size_t o = 3 * rowsz + (size_t)TAGS * 64 * sizeof(float);
  int* off   = (int*)(ws + o);  o += (size_t)(N + 1) * sizeof(int);
  int* bcur  = (int*)(ws + o);  o += (size_t)NBUK * sizeof(int);
  o = (o + 7) & ~(size_t)7;
  int2* rec = (int2*)(ws + o);             // E records (src, w)
  int2* stage = (int2*)b2;                 // NBUK x CAP staged records (14.2 MB)
  float* pb = b1;                          // KSPLIT=2 x NI x 64 partials
                                           // (21 MB, fits b1 -> disjoint from
                                           // stage=b2 read by concurrent passB2)
  float* h  = b1;                          // final embeddings, in-place over b1

  const int nA = E / 2048;                 // 768 passA blocks
  const int nPrep = (N + TAGS + 3) / 4;    // prep blocks
  const int nHyper = (NI / 128) * KSPLIT;  // 640 hyper blocks

  hipMemsetAsync(bcur, 0, (size_t)NBUK * sizeof(int), stream);
  // mega1: passA || prep (independent outputs)
  k_mega1<<<nA + nPrep, 256, 0, stream>>>(esrc, edst, ew, bcur, stage,
                                          emb, ugr, Tw, xt, gkg, N, NU, TAGS, nA);
  // mega2: passB2 (stage->rec/off) || hyper (sps,gkg->pb); disjoint buffers
  k_mega2<<<NBUK + nHyper, 256, 0, stream>>>(stage, bcur, off, rec,
                                             sps, gkg, pb, NI, N, E);
  k_combine<<<(NI + 3) / 4, 256, 0, stream>>>(pb, xt, NI, NU);

  // 3 encoder layers (gather-side); layer 3 fused with expmap
  k_gather<<<(N + 3) / 4, 256, 0, stream>>>(xt, b1, off, rec, N);
  k_gather<<<(N + 3) / 4, 256, 0, stream>>>(b1, b2, off, rec, N);
  k_gather_exp<<<(N + 3) / 4, 256, 0, stream>>>(b2, b1, b2, off, rec, h, N);

  k_score<<<(B / 4 + 3) / 4, 256, 0, stream>>>(h, idx, out, B);
}